// Round 11
// baseline (93.576 us; speedup 1.0000x reference)
//
#include <hip/hip_runtime.h>
#include <hip/hip_bf16.h>

// Problem constants
#define BB 2
#define CC 512
#define NN 2048          // T*H*W = 8*16*16
#define NHEADS 8
#define HDIM 64
#define NSPLIT 4
#define KVQ 512          // NN / NSPLIT

typedef __attribute__((ext_vector_type(8))) __bf16 bf16x8;
typedef __attribute__((ext_vector_type(4))) __bf16 bf16x4;
typedef __attribute__((ext_vector_type(2))) __bf16 bf16x2;
typedef __attribute__((ext_vector_type(4))) float f32x4;

typedef const __attribute__((address_space(1))) unsigned int guint;
typedef __attribute__((address_space(3))) unsigned int suint;

#define QSCALE 0.18033688f  // 0.125 * log2(e): QK^T lands in exp2 domain
#define MFIX 32.0f          // fixed softmax "max": P = exp2(S - 32)

// ---------------------------------------------------------------------------
// Kernel 1: LayerNorm statistics. 256 blocks x 16 tokens.
// ---------------------------------------------------------------------------
__global__ __launch_bounds__(256) void ln_stats_kernel(
    const float* __restrict__ x, float* __restrict__ mu, float* __restrict__ rstd) {
  __shared__ float rs[16][16];
  __shared__ float rq[16][16];
  int tl = threadIdx.x & 15;   // token within block
  int cg = threadIdx.x >> 4;   // channel group (32 ch each)
  int tok = blockIdx.x * 16 + tl;
  int b = tok >> 11;
  int n = tok & (NN - 1);
  const float* xp = x + (size_t)b * CC * NN + n;
  float s = 0.f, ss = 0.f;
  int c0 = cg * 32;
#pragma unroll 8
  for (int c = c0; c < c0 + 32; ++c) {
    float v = xp[(size_t)c * NN];
    s += v;
    ss += v * v;
  }
  rs[cg][tl] = s;
  rq[cg][tl] = ss;
  __syncthreads();
  if (threadIdx.x < 16) {
    int t = threadIdx.x;
    float S = 0.f, SS = 0.f;
#pragma unroll
    for (int gidx = 0; gidx < 16; ++gidx) {
      S += rs[gidx][t];
      SS += rq[gidx][t];
    }
    float m = S * (1.0f / CC);
    float var = SS * (1.0f / CC) - m * m;
    int tk = blockIdx.x * 16 + t;
    mu[tk] = m;
    rstd[tk] = rsqrtf(var + 1e-5f);
  }
}

// ---------------------------------------------------------------------------
// Kernel 1b: LN apply + transpose: x[b][c][n] fp32 -> xln_t[b][n][c] bf16.
// ---------------------------------------------------------------------------
__global__ __launch_bounds__(256) void ln_transpose_kernel(
    const float* __restrict__ x, const float* __restrict__ mu,
    const float* __restrict__ rstd, const float* __restrict__ lnw,
    const float* __restrict__ lnb, __bf16* __restrict__ xln_t) {
  __shared__ float Xs[64][68];
  int n0 = blockIdx.x * 64;
  int c0 = blockIdx.y * 64;
  int b = blockIdx.z;
  int tid = threadIdx.x;
#pragma unroll
  for (int l = 0; l < 4; ++l) {
    int e = tid + 256 * l;
    int row = e >> 4, c4 = e & 15;
    float4 v = *(const float4*)&x[((size_t)b * CC + c0 + row) * NN + n0 + c4 * 4];
    *(float4*)&Xs[row][c4 * 4] = v;
  }
  __syncthreads();
  int sr = tid >> 2;
  int sc = (tid & 3) * 16;
  int tok = b * NN + n0 + sr;
  float mun = mu[tok], rsn = rstd[tok];
  __bf16 outv[16];
#pragma unroll
  for (int j = 0; j < 16; ++j) {
    int c = c0 + sc + j;
    outv[j] = (__bf16)((Xs[sc + j][sr] - mun) * rsn * lnw[c] + lnb[c]);
  }
  __bf16* dst = &xln_t[((size_t)b * NN + n0 + sr) * CC + c0 + sc];
  *(bf16x8*)&dst[0] = *(bf16x8*)&outv[0];
  *(bf16x8*)&dst[8] = *(bf16x8*)&outv[8];
}

// ---------------------------------------------------------------------------
// Kernel 2: merged QKV GEMM, bf16 MFMA, reg-staged double-buffered LDS,
// ONE barrier per K-step. blockIdx.y<16 -> q/k (swapped mfma, [n][d] out);
// else -> v ([c][n] out).
// ---------------------------------------------------------------------------
__global__ __launch_bounds__(256) void qkv_mfma_kernel(
    const __bf16* __restrict__ xln_t, const float* __restrict__ w,
    const float* __restrict__ bias, __bf16* __restrict__ qt,
    __bf16* __restrict__ kt, __bf16* __restrict__ vbf) {
  __shared__ __align__(16) __bf16 As[2][64][68];   // 17.0 KiB
  __shared__ __align__(16) __bf16 Bs[2][128][68];  // 34.0 KiB
  int n0 = blockIdx.x * 128;
  bool swap = blockIdx.y < 16;
  int m0 = swap ? blockIdx.y * 64 : 1024 + ((int)blockIdx.y - 16) * 64;
  int b = blockIdx.z;
  int tid = threadIdx.x;
  int wid = tid >> 6, lane = tid & 63;
  int g = lane >> 4, c = lane & 15;
  int wr = wid >> 1, wc = wid & 1;
  const __bf16* xln = xln_t + (size_t)b * NN * CC;
  int arow = tid >> 4, ac4 = tid & 15;
  int brow = tid >> 3, bc8 = tid & 7;

  float4 wA[4];
  bf16x8 xB[4];
  auto LOADREGS = [&](int k0) {
#pragma unroll
    for (int l = 0; l < 4; ++l)
      wA[l] = *(const float4*)&w[(size_t)(m0 + arow + 16 * l) * CC + k0 + ac4 * 4];
#pragma unroll
    for (int l = 0; l < 4; ++l)
      xB[l] = *(const bf16x8*)&xln[(size_t)(n0 + brow + 32 * l) * CC + k0 + bc8 * 8];
  };
  auto STORELDS = [&](int buf) {
#pragma unroll
    for (int l = 0; l < 4; ++l) {
      bf16x4 pk = {(__bf16)wA[l].x, (__bf16)wA[l].y, (__bf16)wA[l].z,
                   (__bf16)wA[l].w};
      *(bf16x4*)&As[buf][arow + 16 * l][ac4 * 4] = pk;
    }
#pragma unroll
    for (int l = 0; l < 4; ++l)
      *(bf16x8*)&Bs[buf][brow + 32 * l][bc8 * 8] = xB[l];
  };

  LOADREGS(0);
  STORELDS(0);
  __syncthreads();
  f32x4 acc[2][4] = {};
  for (int ktile = 0; ktile < 8; ++ktile) {
    int cur = ktile & 1;
    if (ktile < 7) LOADREGS((ktile + 1) * 64);
#pragma unroll
    for (int hh = 0; hh < 2; ++hh) {
      bf16x8 af[2], bfr[4];
#pragma unroll
      for (int mi = 0; mi < 2; ++mi)
        af[mi] = *(const bf16x8*)&As[cur][wr * 32 + mi * 16 + c][hh * 32 + g * 8];
#pragma unroll
      for (int nj = 0; nj < 4; ++nj)
        bfr[nj] = *(const bf16x8*)&Bs[cur][wc * 64 + nj * 16 + c][hh * 32 + g * 8];
      if (swap) {
#pragma unroll
        for (int mi = 0; mi < 2; ++mi)
#pragma unroll
          for (int nj = 0; nj < 4; ++nj)
            acc[mi][nj] = __builtin_amdgcn_mfma_f32_16x16x32_bf16(
                bfr[nj], af[mi], acc[mi][nj], 0, 0, 0);
      } else {
#pragma unroll
        for (int mi = 0; mi < 2; ++mi)
#pragma unroll
          for (int nj = 0; nj < 4; ++nj)
            acc[mi][nj] = __builtin_amdgcn_mfma_f32_16x16x32_bf16(
                af[mi], bfr[nj], acc[mi][nj], 0, 0, 0);
      }
    }
    if (ktile < 7) STORELDS(cur ^ 1);
    __syncthreads();
  }
  if (swap) {
    int obase = m0 + wr * 32;
    int sec = obase >> 9;  // 0=q, 1=k
    int osec = obase & 511;
    int head = osec >> 6;
    int dbase = osec & 63;
    __bf16* dst = (sec == 0 ? qt : kt) + (size_t)(b * NHEADS + head) * NN * HDIM;
    float scl = (sec == 0) ? QSCALE : 1.0f;
#pragma unroll
    for (int mi = 0; mi < 2; ++mi) {
      float bo = bias[obase + mi * 16 + c];
      int d = dbase + mi * 16 + c;
#pragma unroll
      for (int nj = 0; nj < 4; ++nj)
#pragma unroll
        for (int r = 0; r < 4; ++r) {
          int n = n0 + wc * 64 + nj * 16 + 4 * g + r;
          dst[(size_t)n * HDIM + d] = (__bf16)((acc[mi][nj][r] + bo) * scl);
        }
    }
  } else {
#pragma unroll
    for (int mi = 0; mi < 2; ++mi)
#pragma unroll
      for (int r = 0; r < 4; ++r) {
        int o = m0 + wr * 32 + mi * 16 + 4 * g + r;
        int ch = o - 1024;
        float bo = bias[o];
#pragma unroll
        for (int nj = 0; nj < 4; ++nj) {
          int n = n0 + wc * 64 + nj * 16 + c;
          vbf[((size_t)b * CC + ch) * NN + n] = (__bf16)(acc[mi][nj][r] + bo);
        }
      }
  }
}

// ---------------------------------------------------------------------------
// Kernel 3: flash attention, split-KV x4, 4 waves x 256 thr, QBLK=128,
// 2 q-groups per wave. FIXED-MAX softmax: P = exp2(S - 32), the -32 baked
// into the QK^T MFMA C-initializer (zero VALU cost). No max tracking, no
// rescale, no shuffles in the loop — softmax is a pure exp2+pack+add stream.
// K/V staged via global_load_lds, XOR chunk swizzle (0 bank conflicts, R9).
// ---------------------------------------------------------------------------
__global__ __launch_bounds__(256, 4) void attn_mfma_kernel(
    const __bf16* __restrict__ qt, const __bf16* __restrict__ ktg,
    const __bf16* __restrict__ vbf, __bf16* __restrict__ opart,
    float* __restrict__ lbuf) {
  __shared__ __align__(16) __bf16 Kb[2][64][64];  // 16 KiB
  __shared__ __align__(16) __bf16 Vb[2][64][64];  // 16 KiB
  int tid = threadIdx.x;
  int wid = tid >> 6, lane = tid & 63;
  int g = lane >> 4, c = lane & 15;
  int n0 = blockIdx.x * 128;
  int h = blockIdx.y;
  int b = blockIdx.z >> 2, split = blockIdx.z & 3;
  int bh = b * NHEADS + h;
  const __bf16* qbase = qt + ((size_t)bh * NN + n0) * HDIM;
  const __bf16* kbase = ktg + ((size_t)bh * NN + split * KVQ) * HDIM;
  const __bf16* vbase = vbf + ((size_t)b * CC + h * HDIM) * NN + split * KVQ;

  int l7 = lane & 7, l3 = lane >> 3;  // dest chunk, row-within-8
  int xr = (l7 ^ l3) * 8;             // XOR-swizzled source chunk (elements)
  auto STAGE = [&](int buf, int mt) {
#pragma unroll
    for (int j = 0; j < 2; ++j) {
      int r = wid * 16 + 8 * j + l3;  // dest row; r&7 == l3
      // K: dest row r holds logical K row inv(r) (inverse of the PV-layout
      // permutation p(i) = (i>>5)<<5 | ((i>>2)&1)<<4 | ((i>>3)&3)<<2 | (i&3))
      int gr = (r & 0x20) | (((r >> 2) & 3) << 3) | (((r >> 4) & 1) << 2) | (r & 3);
      const __bf16* ksrc = kbase + (size_t)(mt + gr) * HDIM + xr;
      __builtin_amdgcn_global_load_lds((guint*)ksrc,
                                       (suint*)&Kb[buf][wid * 16 + 8 * j][0],
                                       16, 0, 0);
      const __bf16* vsrc = vbase + (size_t)r * NN + mt + xr;
      __builtin_amdgcn_global_load_lds((guint*)vsrc,
                                       (suint*)&Vb[buf][wid * 16 + 8 * j][0],
                                       16, 0, 0);
    }
  };

  STAGE(0, 0);
  // Q fragments for both q-groups (held in regs for the whole kernel)
  bf16x8 aq[2][2];
#pragma unroll
  for (int qg = 0; qg < 2; ++qg) {
    const __bf16* qp = qbase + (size_t)(wid * 32 + qg * 16 + c) * HDIM;
    aq[qg][0] = *(const bf16x8*)(qp + g * 8);
    aq[qg][1] = *(const bf16x8*)(qp + 32 + g * 8);
  }
  f32x4 O[2][4] = {};   // O^T per qg: O[qg][dt][r] = O^T[d=dt*16+4g+r][q=c]
  float l_[2] = {0.f, 0.f};  // per-lane partial sums of P
  int cxor = (c & 7);   // read-side XOR (row&7 == c&7 for rows t4*16+c)
  const f32x4 cinit = {-MFIX, -MFIX, -MFIX, -MFIX};
  __syncthreads();

  for (int t = 0; t < KVQ / 64; ++t) {
    int cur = t & 1;
    if (t + 1 < KVQ / 64) STAGE(cur ^ 1, (t + 1) * 64);
    // ---- QK^T swapped; C initialized to -32 so st = S - 32 ----
    f32x4 st[2][4];
    __builtin_amdgcn_s_setprio(1);
#pragma unroll
    for (int t4 = 0; t4 < 4; ++t4) {
      bf16x8 bk0 = *(const bf16x8*)&Kb[cur][t4 * 16 + c][(g ^ cxor) * 8];
      bf16x8 bk1 = *(const bf16x8*)&Kb[cur][t4 * 16 + c][((4 + g) ^ cxor) * 8];
#pragma unroll
      for (int qg = 0; qg < 2; ++qg) {
        f32x4 acc = __builtin_amdgcn_mfma_f32_16x16x32_bf16(bk0, aq[qg][0],
                                                            cinit, 0, 0, 0);
        acc = __builtin_amdgcn_mfma_f32_16x16x32_bf16(bk1, aq[qg][1], acc, 0, 0, 0);
        st[qg][t4] = acc;
      }
    }
    __builtin_amdgcn_s_setprio(0);
    // ---- fixed-max softmax: pure exp2 + pack + tree-add (no shuffles) ----
    bf16x8 pa[2][2];
#pragma unroll
    for (int qg = 0; qg < 2; ++qg) {
      float pt[4];
#pragma unroll
      for (int t4 = 0; t4 < 4; ++t4) {
        float p0 = exp2f(st[qg][t4][0]);
        float p1 = exp2f(st[qg][t4][1]);
        float p2 = exp2f(st[qg][t4][2]);
        float p3 = exp2f(st[qg][t4][3]);
        pt[t4] = (p0 + p1) + (p2 + p3);
        bf16x8* pp = &pa[qg][t4 >> 1];
        int o4 = (t4 & 1) * 4;
        (*pp)[o4 + 0] = (__bf16)p0;
        (*pp)[o4 + 1] = (__bf16)p1;
        (*pp)[o4 + 2] = (__bf16)p2;
        (*pp)[o4 + 3] = (__bf16)p3;
      }
      l_[qg] += (pt[0] + pt[1]) + (pt[2] + pt[3]);
    }
    // ---- PV swapped: each V fragment read feeds both q-groups ----
    __builtin_amdgcn_s_setprio(1);
#pragma unroll
    for (int dt = 0; dt < 4; ++dt) {
      bf16x8 bv0 = *(const bf16x8*)&Vb[cur][dt * 16 + c][(g ^ cxor) * 8];
      bf16x8 bv1 = *(const bf16x8*)&Vb[cur][dt * 16 + c][((4 + g) ^ cxor) * 8];
#pragma unroll
      for (int qg = 0; qg < 2; ++qg) {
        O[qg][dt] = __builtin_amdgcn_mfma_f32_16x16x32_bf16(bv0, pa[qg][0],
                                                            O[qg][dt], 0, 0, 0);
        O[qg][dt] = __builtin_amdgcn_mfma_f32_16x16x32_bf16(bv1, pa[qg][1],
                                                            O[qg][dt], 0, 0, 0);
      }
    }
    __builtin_amdgcn_s_setprio(0);
    __syncthreads();  // drains staging vmcnt; next buffer ready
  }
  // ---- epilogue: unnormalized bf16 partials + l per q-group ----
#pragma unroll
  for (int qg = 0; qg < 2; ++qg) {
    float lt = l_[qg] + __shfl_xor(l_[qg], 16);
    lt += __shfl_xor(lt, 32);
    size_t prow = ((size_t)(split * BB + b) * NHEADS + h) * NN +
                  (n0 + wid * 32 + qg * 16 + c);
#pragma unroll
    for (int dt = 0; dt < 4; ++dt) {
      bf16x4 pk = {(__bf16)O[qg][dt][0], (__bf16)O[qg][dt][1],
                   (__bf16)O[qg][dt][2], (__bf16)O[qg][dt][3]};
      *(bf16x4*)&opart[prow * HDIM + dt * 16 + 4 * g] = pk;
    }
    if (lane < 16) lbuf[prow] = lt;
  }
}

// ---------------------------------------------------------------------------
// Kernel 3b: combine the four KV-split partials -> xa_t[b][n][c] bf16.
// All splits share the fixed max => plain sums, no exp2.
// ---------------------------------------------------------------------------
__global__ __launch_bounds__(256) void attn_combine_kernel(
    const __bf16* __restrict__ opart, const float* __restrict__ lbuf,
    __bf16* __restrict__ xa_t) {
  int t = threadIdx.x;
  int row_local = t >> 4;          // 0..15
  int dq = (t & 15) * 4;           // 0..60
  int R = blockIdx.x * 16 + row_local;  // global (b,h,n) row, 0..32767
  int n = R & (NN - 1);
  int bh = R >> 11;
  int b = bh >> 3, h = bh & 7;
  float lsum = 0.f;
  float acc[4] = {0.f, 0.f, 0.f, 0.f};
#pragma unroll
  for (int s = 0; s < NSPLIT; ++s) {
    size_t p = ((size_t)(s * BB + b) * NHEADS + h) * NN + n;
    lsum += lbuf[p];
    bf16x4 ov = *(const bf16x4*)&opart[p * HDIM + dq];
#pragma unroll
    for (int j = 0; j < 4; ++j) acc[j] += (float)ov[j];
  }
  float linv = 1.0f / lsum;
  bf16x4 pk = {(__bf16)(acc[0] * linv), (__bf16)(acc[1] * linv),
               (__bf16)(acc[2] * linv), (__bf16)(acc[3] * linv)};
  *(bf16x4*)&xa_t[((size_t)b * NN + n) * CC + h * HDIM + dq] = pk;
}

// ---------------------------------------------------------------------------
// Kernel 4: proj GEMM, reg-staged double-buffered LDS, 1 barrier per K-step,
// bias + residual(normalized x, fp32) epilogue.
// ---------------------------------------------------------------------------
__global__ __launch_bounds__(256) void proj_mfma_kernel(
    const __bf16* __restrict__ xa_t, const float* __restrict__ w,
    const float* __restrict__ bias, const float* __restrict__ x,
    const float* __restrict__ mu, const float* __restrict__ rstd,
    const float* __restrict__ lnw, const float* __restrict__ lnb,
    float* __restrict__ out) {
  __shared__ __align__(16) __bf16 As[2][64][68];
  __shared__ __align__(16) __bf16 Bs[2][64][68];
  int n0 = blockIdx.x * 64;
  int m0 = blockIdx.y * 64;
  int b = blockIdx.z;
  int tid = threadIdx.x;
  int wid = tid >> 6, lane = tid & 63;
  int g = lane >> 4, c = lane & 15;
  int wr = wid >> 1, wc = wid & 1;
  const __bf16* xab = xa_t + (size_t)b * NN * CC;
  int arow = tid >> 4, ac4 = tid & 15;
  int brow = tid >> 3, bc8 = tid & 7;

  float4 wA[4];
  bf16x8 xB[2];
  auto LOADREGS = [&](int k0) {
#pragma unroll
    for (int l = 0; l < 4; ++l)
      wA[l] = *(const float4*)&w[(size_t)(m0 + arow + 16 * l) * CC + k0 + ac4 * 4];
#pragma unroll
    for (int l = 0; l < 2; ++l)
      xB[l] = *(const bf16x8*)&xab[(size_t)(n0 + brow + 32 * l) * CC + k0 + bc8 * 8];
  };
  auto STORELDS = [&](int buf) {
#pragma unroll
    for (int l = 0; l < 4; ++l) {
      bf16x4 pk = {(__bf16)wA[l].x, (__bf16)wA[l].y, (__bf16)wA[l].z,
                   (__bf16)wA[l].w};
      *(bf16x4*)&As[buf][arow + 16 * l][ac4 * 4] = pk;
    }
#pragma unroll
    for (int l = 0; l < 2; ++l)
      *(bf16x8*)&Bs[buf][brow + 32 * l][bc8 * 8] = xB[l];
  };

  LOADREGS(0);
  STORELDS(0);
  __syncthreads();
  f32x4 acc[2][2] = {};
  for (int ktile = 0; ktile < 8; ++ktile) {
    int cur = ktile & 1;
    if (ktile < 7) LOADREGS((ktile + 1) * 64);
#pragma unroll
    for (int hh = 0; hh < 2; ++hh) {
      bf16x8 af[2], bfr[2];
#pragma unroll
      for (int mi = 0; mi < 2; ++mi)
        af[mi] = *(const bf16x8*)&As[cur][wr * 32 + mi * 16 + c][hh * 32 + g * 8];
#pragma unroll
      for (int nj = 0; nj < 2; ++nj)
        bfr[nj] = *(const bf16x8*)&Bs[cur][wc * 32 + nj * 16 + c][hh * 32 + g * 8];
#pragma unroll
      for (int mi = 0; mi < 2; ++mi)
#pragma unroll
        for (int nj = 0; nj < 2; ++nj)
          acc[mi][nj] = __builtin_amdgcn_mfma_f32_16x16x32_bf16(
              af[mi], bfr[nj], acc[mi][nj], 0, 0, 0);
    }
    if (ktile < 7) STORELDS(cur ^ 1);
    __syncthreads();
  }
#pragma unroll
  for (int mi = 0; mi < 2; ++mi)
#pragma unroll
    for (int r = 0; r < 4; ++r) {
      int o = m0 + wr * 32 + mi * 16 + 4 * g + r;
      float bo = bias[o], gw = lnw[o], gb = lnb[o];
#pragma unroll
      for (int nj = 0; nj < 2; ++nj) {
        int n = n0 + wc * 32 + nj * 16 + c;
        int tok = b * NN + n;
        float xv = x[((size_t)b * CC + o) * NN + n];
        float xlnv = (xv - mu[tok]) * rstd[tok] * gw + gb;
        out[((size_t)b * CC + o) * NN + n] = acc[mi][nj][r] + bo + xlnv;
      }
    }
}

// ---------------------------------------------------------------------------
extern "C" void kernel_launch(void* const* d_in, const int* in_sizes, int n_in,
                              void* d_out, int out_size, void* d_ws, size_t ws_size,
                              hipStream_t stream) {
  const float* x = (const float*)d_in[0];
  const float* lnw = (const float*)d_in[1];
  const float* lnb = (const float*)d_in[2];
  const float* wqkv = (const float*)d_in[3];
  const float* bqkv = (const float*)d_in[4];
  const float* wproj = (const float*)d_in[5];
  const float* bproj = (const float*)d_in[6];
  float* out = (float*)d_out;
  (void)in_sizes; (void)n_in; (void)out_size; (void)ws_size;

  char* wsb = (char*)d_ws;
  float* mu = (float*)wsb;                               // 16 KB
  float* rstd = mu + 4096;                               // 16 KB
  const size_t HSZ = (size_t)BB * NHEADS * NN * HDIM;    // 2M elems
  __bf16* qt = (__bf16*)(wsb + 32768);                   // 4 MB
  __bf16* kt = qt + HSZ;                                 // 4 MB
  __bf16* vbf = kt + HSZ;                                // 4 MB
  __bf16* xa_t = vbf + HSZ;                              // 4 MB
  __bf16* xln_t = xa_t + HSZ;                            // 4 MB (dead after qkv)
  // opart overlays xln_t's region and extends: 4 splits x 4 MB bf16 = 16 MB
  __bf16* opart = xln_t;
  float* lbuf = (float*)(wsb + 32768 + 4 * HSZ * sizeof(__bf16) +
                         (size_t)NSPLIT * HSZ * sizeof(__bf16));  // 512 KB

  hipLaunchKernelGGL(ln_stats_kernel, dim3(256), dim3(256), 0, stream, x, mu, rstd);
  hipLaunchKernelGGL(ln_transpose_kernel, dim3(32, 8, 2), dim3(256), 0, stream,
                     x, mu, rstd, lnw, lnb, xln_t);
  hipLaunchKernelGGL(qkv_mfma_kernel, dim3(16, 24, 2), dim3(256), 0, stream,
                     xln_t, wqkv, bqkv, qt, kt, vbf);
  hipLaunchKernelGGL(attn_mfma_kernel, dim3(16, 8, BB * NSPLIT), dim3(256), 0,
                     stream, qt, kt, vbf, opart, lbuf);
  hipLaunchKernelGGL(attn_combine_kernel, dim3(2048), dim3(256), 0, stream,
                     opart, lbuf, xa_t);
  hipLaunchKernelGGL(proj_mfma_kernel, dim3(32, 8, 2), dim3(256), 0, stream,
                     xa_t, wproj, bproj, x, mu, rstd, lnw, lnb, out);
}

// Round 12
// 79.918 us; speedup vs baseline: 1.1709x; 1.1709x over previous
//
#include <hip/hip_runtime.h>
#include <hip/hip_bf16.h>

// Problem constants
#define BB 2
#define CC 512
#define NN 2048          // T*H*W = 8*16*16
#define NHEADS 8
#define HDIM 64
#define NSPLIT 4
#define KVQ 512          // NN / NSPLIT

typedef __attribute__((ext_vector_type(8))) __bf16 bf16x8;
typedef __attribute__((ext_vector_type(4))) __bf16 bf16x4;
typedef __attribute__((ext_vector_type(2))) __bf16 bf16x2;
typedef __attribute__((ext_vector_type(4))) float f32x4;

typedef const __attribute__((address_space(1))) unsigned int guint;
typedef __attribute__((address_space(3))) unsigned int suint;

#define QSCALE 0.18033688f  // 0.125 * log2(e): QK^T lands in exp2 domain
#define MX3(a, b, c) fmaxf(fmaxf(a, b), c)

// ---------------------------------------------------------------------------
// Kernel 1: LayerNorm statistics. 256 blocks x 16 tokens.
// ---------------------------------------------------------------------------
__global__ __launch_bounds__(256) void ln_stats_kernel(
    const float* __restrict__ x, float* __restrict__ mu, float* __restrict__ rstd) {
  __shared__ float rs[16][16];
  __shared__ float rq[16][16];
  int tl = threadIdx.x & 15;   // token within block
  int cg = threadIdx.x >> 4;   // channel group (32 ch each)
  int tok = blockIdx.x * 16 + tl;
  int b = tok >> 11;
  int n = tok & (NN - 1);
  const float* xp = x + (size_t)b * CC * NN + n;
  float s = 0.f, ss = 0.f;
  int c0 = cg * 32;
#pragma unroll 8
  for (int c = c0; c < c0 + 32; ++c) {
    float v = xp[(size_t)c * NN];
    s += v;
    ss += v * v;
  }
  rs[cg][tl] = s;
  rq[cg][tl] = ss;
  __syncthreads();
  if (threadIdx.x < 16) {
    int t = threadIdx.x;
    float S = 0.f, SS = 0.f;
#pragma unroll
    for (int gidx = 0; gidx < 16; ++gidx) {
      S += rs[gidx][t];
      SS += rq[gidx][t];
    }
    float m = S * (1.0f / CC);
    float var = SS * (1.0f / CC) - m * m;
    int tk = blockIdx.x * 16 + t;
    mu[tk] = m;
    rstd[tk] = rsqrtf(var + 1e-5f);
  }
}

// ---------------------------------------------------------------------------
// Kernel 1b: LN apply + transpose: x[b][c][n] fp32 -> xln_t[b][n][c] bf16.
// ---------------------------------------------------------------------------
__global__ __launch_bounds__(256) void ln_transpose_kernel(
    const float* __restrict__ x, const float* __restrict__ mu,
    const float* __restrict__ rstd, const float* __restrict__ lnw,
    const float* __restrict__ lnb, __bf16* __restrict__ xln_t) {
  __shared__ float Xs[64][68];
  int n0 = blockIdx.x * 64;
  int c0 = blockIdx.y * 64;
  int b = blockIdx.z;
  int tid = threadIdx.x;
#pragma unroll
  for (int l = 0; l < 4; ++l) {
    int e = tid + 256 * l;
    int row = e >> 4, c4 = e & 15;
    float4 v = *(const float4*)&x[((size_t)b * CC + c0 + row) * NN + n0 + c4 * 4];
    *(float4*)&Xs[row][c4 * 4] = v;
  }
  __syncthreads();
  int sr = tid >> 2;
  int sc = (tid & 3) * 16;
  int tok = b * NN + n0 + sr;
  float mun = mu[tok], rsn = rstd[tok];
  __bf16 outv[16];
#pragma unroll
  for (int j = 0; j < 16; ++j) {
    int c = c0 + sc + j;
    outv[j] = (__bf16)((Xs[sc + j][sr] - mun) * rsn * lnw[c] + lnb[c]);
  }
  __bf16* dst = &xln_t[((size_t)b * NN + n0 + sr) * CC + c0 + sc];
  *(bf16x8*)&dst[0] = *(bf16x8*)&outv[0];
  *(bf16x8*)&dst[8] = *(bf16x8*)&outv[8];
}

// ---------------------------------------------------------------------------
// Kernel 2: merged QKV GEMM, bf16 MFMA, reg-staged double-buffered LDS,
// ONE barrier per K-step. blockIdx.y<16 -> q/k (swapped mfma, [n][d] out);
// else -> v ([c][n] out).
// ---------------------------------------------------------------------------
__global__ __launch_bounds__(256) void qkv_mfma_kernel(
    const __bf16* __restrict__ xln_t, const float* __restrict__ w,
    const float* __restrict__ bias, __bf16* __restrict__ qt,
    __bf16* __restrict__ kt, __bf16* __restrict__ vbf) {
  __shared__ __align__(16) __bf16 As[2][64][68];   // 17.0 KiB
  __shared__ __align__(16) __bf16 Bs[2][128][68];  // 34.0 KiB
  int n0 = blockIdx.x * 128;
  bool swap = blockIdx.y < 16;
  int m0 = swap ? blockIdx.y * 64 : 1024 + ((int)blockIdx.y - 16) * 64;
  int b = blockIdx.z;
  int tid = threadIdx.x;
  int wid = tid >> 6, lane = tid & 63;
  int g = lane >> 4, c = lane & 15;
  int wr = wid >> 1, wc = wid & 1;
  const __bf16* xln = xln_t + (size_t)b * NN * CC;
  int arow = tid >> 4, ac4 = tid & 15;
  int brow = tid >> 3, bc8 = tid & 7;

  float4 wA[4];
  bf16x8 xB[4];
  auto LOADREGS = [&](int k0) {
#pragma unroll
    for (int l = 0; l < 4; ++l)
      wA[l] = *(const float4*)&w[(size_t)(m0 + arow + 16 * l) * CC + k0 + ac4 * 4];
#pragma unroll
    for (int l = 0; l < 4; ++l)
      xB[l] = *(const bf16x8*)&xln[(size_t)(n0 + brow + 32 * l) * CC + k0 + bc8 * 8];
  };
  auto STORELDS = [&](int buf) {
#pragma unroll
    for (int l = 0; l < 4; ++l) {
      bf16x4 pk = {(__bf16)wA[l].x, (__bf16)wA[l].y, (__bf16)wA[l].z,
                   (__bf16)wA[l].w};
      *(bf16x4*)&As[buf][arow + 16 * l][ac4 * 4] = pk;
    }
#pragma unroll
    for (int l = 0; l < 4; ++l)
      *(bf16x8*)&Bs[buf][brow + 32 * l][bc8 * 8] = xB[l];
  };

  LOADREGS(0);
  STORELDS(0);
  __syncthreads();
  f32x4 acc[2][4] = {};
  for (int ktile = 0; ktile < 8; ++ktile) {
    int cur = ktile & 1;
    if (ktile < 7) LOADREGS((ktile + 1) * 64);
#pragma unroll
    for (int hh = 0; hh < 2; ++hh) {
      bf16x8 af[2], bfr[4];
#pragma unroll
      for (int mi = 0; mi < 2; ++mi)
        af[mi] = *(const bf16x8*)&As[cur][wr * 32 + mi * 16 + c][hh * 32 + g * 8];
#pragma unroll
      for (int nj = 0; nj < 4; ++nj)
        bfr[nj] = *(const bf16x8*)&Bs[cur][wc * 64 + nj * 16 + c][hh * 32 + g * 8];
      if (swap) {
#pragma unroll
        for (int mi = 0; mi < 2; ++mi)
#pragma unroll
          for (int nj = 0; nj < 4; ++nj)
            acc[mi][nj] = __builtin_amdgcn_mfma_f32_16x16x32_bf16(
                bfr[nj], af[mi], acc[mi][nj], 0, 0, 0);
      } else {
#pragma unroll
        for (int mi = 0; mi < 2; ++mi)
#pragma unroll
          for (int nj = 0; nj < 4; ++nj)
            acc[mi][nj] = __builtin_amdgcn_mfma_f32_16x16x32_bf16(
                af[mi], bfr[nj], acc[mi][nj], 0, 0, 0);
      }
    }
    if (ktile < 7) STORELDS(cur ^ 1);
    __syncthreads();
  }
  if (swap) {
    int obase = m0 + wr * 32;
    int sec = obase >> 9;  // 0=q, 1=k
    int osec = obase & 511;
    int head = osec >> 6;
    int dbase = osec & 63;
    __bf16* dst = (sec == 0 ? qt : kt) + (size_t)(b * NHEADS + head) * NN * HDIM;
    float scl = (sec == 0) ? QSCALE : 1.0f;
#pragma unroll
    for (int mi = 0; mi < 2; ++mi) {
      float bo = bias[obase + mi * 16 + c];
      int d = dbase + mi * 16 + c;
#pragma unroll
      for (int nj = 0; nj < 4; ++nj)
#pragma unroll
        for (int r = 0; r < 4; ++r) {
          int n = n0 + wc * 64 + nj * 16 + 4 * g + r;
          dst[(size_t)n * HDIM + d] = (__bf16)((acc[mi][nj][r] + bo) * scl);
        }
    }
  } else {
#pragma unroll
    for (int mi = 0; mi < 2; ++mi)
#pragma unroll
      for (int r = 0; r < 4; ++r) {
        int o = m0 + wr * 32 + mi * 16 + 4 * g + r;
        int ch = o - 1024;
        float bo = bias[o];
#pragma unroll
        for (int nj = 0; nj < 4; ++nj) {
          int n = n0 + wc * 64 + nj * 16 + c;
          vbf[((size_t)b * CC + ch) * NN + n] = (__bf16)(acc[mi][nj][r] + bo);
        }
      }
  }
}

// ---------------------------------------------------------------------------
// Kernel 3: flash attention, split-KV x4, 4 waves x 256 thr, QBLK=128,
// 2 q-groups per wave. R10 defer-rescale structure, plus:
//  - lane-local defer check (__all reduces across lanes; NO hot-path shuffles)
//  - l accumulated via ones-row MFMA (kills the add tree + epilogue shuffles)
//  - max via v_max3 tree (8 ops for 16 values)
// K/V staged via global_load_lds, XOR chunk swizzle (0 bank conflicts, R9).
// launch_bounds(256,3): VGPR cap 170 — avoids the R11 scratch-spill cliff.
// ---------------------------------------------------------------------------
__global__ __launch_bounds__(256, 3) void attn_mfma_kernel(
    const __bf16* __restrict__ qt, const __bf16* __restrict__ ktg,
    const __bf16* __restrict__ vbf, __bf16* __restrict__ opart,
    float* __restrict__ ml) {
  __shared__ __align__(16) __bf16 Kb[2][64][64];  // 16 KiB
  __shared__ __align__(16) __bf16 Vb[2][64][64];  // 16 KiB
  int tid = threadIdx.x;
  int wid = tid >> 6, lane = tid & 63;
  int g = lane >> 4, c = lane & 15;
  int n0 = blockIdx.x * 128;
  int h = blockIdx.y;
  int b = blockIdx.z >> 2, split = blockIdx.z & 3;
  int bh = b * NHEADS + h;
  const __bf16* qbase = qt + ((size_t)bh * NN + n0) * HDIM;
  const __bf16* kbase = ktg + ((size_t)bh * NN + split * KVQ) * HDIM;
  const __bf16* vbase = vbf + ((size_t)b * CC + h * HDIM) * NN + split * KVQ;

  int l7 = lane & 7, l3 = lane >> 3;  // dest chunk, row-within-8
  int xr = (l7 ^ l3) * 8;             // XOR-swizzled source chunk (elements)
  auto STAGE = [&](int buf, int mt) {
#pragma unroll
    for (int j = 0; j < 2; ++j) {
      int r = wid * 16 + 8 * j + l3;  // dest row; r&7 == l3
      // K: dest row r holds logical K row inv(r) (inverse of the PV-layout
      // permutation p(i) = (i>>5)<<5 | ((i>>2)&1)<<4 | ((i>>3)&3)<<2 | (i&3))
      int gr = (r & 0x20) | (((r >> 2) & 3) << 3) | (((r >> 4) & 1) << 2) | (r & 3);
      const __bf16* ksrc = kbase + (size_t)(mt + gr) * HDIM + xr;
      __builtin_amdgcn_global_load_lds((guint*)ksrc,
                                       (suint*)&Kb[buf][wid * 16 + 8 * j][0],
                                       16, 0, 0);
      const __bf16* vsrc = vbase + (size_t)r * NN + mt + xr;
      __builtin_amdgcn_global_load_lds((guint*)vsrc,
                                       (suint*)&Vb[buf][wid * 16 + 8 * j][0],
                                       16, 0, 0);
    }
  };

  STAGE(0, 0);
  // Q fragments for both q-groups (held in regs for the whole kernel)
  bf16x8 aq[2][2];
#pragma unroll
  for (int qg = 0; qg < 2; ++qg) {
    const __bf16* qp = qbase + (size_t)(wid * 32 + qg * 16 + c) * HDIM;
    aq[qg][0] = *(const bf16x8*)(qp + g * 8);
    aq[qg][1] = *(const bf16x8*)(qp + 32 + g * 8);
  }
  f32x4 O[2][4] = {};   // O^T per qg: O[qg][dt][r] = O^T[d=dt*16+4g+r][q=c]
  f32x4 Ol[2] = {};     // ones-row accumulator: Ol[qg][*] = l for q-row c
  float m_[2] = {-1e30f, -1e30f};
  int cxor = (c & 7);   // read-side XOR (row&7 == c&7 for rows t4*16+c)
  const bf16x8 vones = {(__bf16)1.f, (__bf16)1.f, (__bf16)1.f, (__bf16)1.f,
                        (__bf16)1.f, (__bf16)1.f, (__bf16)1.f, (__bf16)1.f};
  __syncthreads();

  for (int t = 0; t < KVQ / 64; ++t) {
    int cur = t & 1;
    if (t + 1 < KVQ / 64) STAGE(cur ^ 1, (t + 1) * 64);
    // ---- QK^T swapped: st[qg][t4][r] = S[q=c][k] ----
    f32x4 st[2][4];
    __builtin_amdgcn_s_setprio(1);
#pragma unroll
    for (int t4 = 0; t4 < 4; ++t4) {
      bf16x8 bk0 = *(const bf16x8*)&Kb[cur][t4 * 16 + c][(g ^ cxor) * 8];
      bf16x8 bk1 = *(const bf16x8*)&Kb[cur][t4 * 16 + c][((4 + g) ^ cxor) * 8];
#pragma unroll
      for (int qg = 0; qg < 2; ++qg) {
        f32x4 acc = {0.f, 0.f, 0.f, 0.f};
        acc = __builtin_amdgcn_mfma_f32_16x16x32_bf16(bk0, aq[qg][0], acc, 0, 0, 0);
        acc = __builtin_amdgcn_mfma_f32_16x16x32_bf16(bk1, aq[qg][1], acc, 0, 0, 0);
        st[qg][t4] = acc;
      }
    }
    __builtin_amdgcn_s_setprio(0);
    // ---- softmax: lane-local max3 tree + defer-rescale (no hot shuffles) ----
    bf16x8 pa[2][2];
#pragma unroll
    for (int qg = 0; qg < 2; ++qg) {
      float g0 = MX3(st[qg][0][0], st[qg][0][1], st[qg][0][2]);
      float g1 = MX3(st[qg][0][3], st[qg][1][0], st[qg][1][1]);
      float g2 = MX3(st[qg][1][2], st[qg][1][3], st[qg][2][0]);
      float g3 = MX3(st[qg][2][1], st[qg][2][2], st[qg][2][3]);
      float g4 = MX3(st[qg][3][0], st[qg][3][1], st[qg][3][2]);
      float pm = fmaxf(MX3(g0, g1, g2), MX3(g3, g4, st[qg][3][3]));
      if (!__all(pm <= m_[qg] + 8.0f)) {  // rare: first iter + occasional
        float rm = fmaxf(pm, __shfl_xor(pm, 16));
        rm = fmaxf(rm, __shfl_xor(rm, 32));
        float mn = fmaxf(m_[qg], rm);
        float fs = exp2f(m_[qg] - mn);
        m_[qg] = mn;
#pragma unroll
        for (int dt = 0; dt < 4; ++dt)
#pragma unroll
          for (int r = 0; r < 4; ++r) O[qg][dt][r] *= fs;
#pragma unroll
        for (int r = 0; r < 4; ++r) Ol[qg][r] *= fs;
      }
#pragma unroll
      for (int t4 = 0; t4 < 4; ++t4) {
        float p0 = exp2f(st[qg][t4][0] - m_[qg]);
        float p1 = exp2f(st[qg][t4][1] - m_[qg]);
        float p2 = exp2f(st[qg][t4][2] - m_[qg]);
        float p3 = exp2f(st[qg][t4][3] - m_[qg]);
        bf16x8* pp = &pa[qg][t4 >> 1];
        int o4 = (t4 & 1) * 4;
        (*pp)[o4 + 0] = (__bf16)p0;
        (*pp)[o4 + 1] = (__bf16)p1;
        (*pp)[o4 + 2] = (__bf16)p2;
        (*pp)[o4 + 3] = (__bf16)p3;
      }
    }
    // ---- PV swapped + ones-row l (each V fragment feeds both q-groups) ----
    __builtin_amdgcn_s_setprio(1);
#pragma unroll
    for (int dt = 0; dt < 4; ++dt) {
      bf16x8 bv0 = *(const bf16x8*)&Vb[cur][dt * 16 + c][(g ^ cxor) * 8];
      bf16x8 bv1 = *(const bf16x8*)&Vb[cur][dt * 16 + c][((4 + g) ^ cxor) * 8];
#pragma unroll
      for (int qg = 0; qg < 2; ++qg) {
        O[qg][dt] = __builtin_amdgcn_mfma_f32_16x16x32_bf16(bv0, pa[qg][0],
                                                            O[qg][dt], 0, 0, 0);
        O[qg][dt] = __builtin_amdgcn_mfma_f32_16x16x32_bf16(bv1, pa[qg][1],
                                                            O[qg][dt], 0, 0, 0);
      }
    }
#pragma unroll
    for (int qg = 0; qg < 2; ++qg) {
      Ol[qg] = __builtin_amdgcn_mfma_f32_16x16x32_bf16(vones, pa[qg][0],
                                                       Ol[qg], 0, 0, 0);
      Ol[qg] = __builtin_amdgcn_mfma_f32_16x16x32_bf16(vones, pa[qg][1],
                                                       Ol[qg], 0, 0, 0);
    }
    __builtin_amdgcn_s_setprio(0);
    __syncthreads();  // drains staging vmcnt; next buffer ready
  }
  // ---- epilogue: unnormalized bf16 partials + (m, l) per q-group ----
#pragma unroll
  for (int qg = 0; qg < 2; ++qg) {
    size_t prow = ((size_t)(split * BB + b) * NHEADS + h) * NN +
                  (n0 + wid * 32 + qg * 16 + c);
#pragma unroll
    for (int dt = 0; dt < 4; ++dt) {
      bf16x4 pk = {(__bf16)O[qg][dt][0], (__bf16)O[qg][dt][1],
                   (__bf16)O[qg][dt][2], (__bf16)O[qg][dt][3]};
      *(bf16x4*)&opart[prow * HDIM + dt * 16 + 4 * g] = pk;
    }
    if (lane < 16) {
      float2 mlv = {m_[qg], Ol[qg][0]};
      *(float2*)&ml[prow * 2] = mlv;
    }
  }
}

// ---------------------------------------------------------------------------
// Kernel 3b: combine the four KV-split partials -> xa_t[b][n][c] bf16.
// ---------------------------------------------------------------------------
__global__ __launch_bounds__(256) void attn_combine_kernel(
    const __bf16* __restrict__ opart, const float* __restrict__ ml,
    __bf16* __restrict__ xa_t) {
  int t = threadIdx.x;
  int row_local = t >> 4;          // 0..15
  int dq = (t & 15) * 4;           // 0..60
  int R = blockIdx.x * 16 + row_local;  // global (b,h,n) row, 0..32767
  int n = R & (NN - 1);
  int bh = R >> 11;
  int b = bh >> 3, h = bh & 7;
  size_t ps[NSPLIT];
  float ms[NSPLIT], ls[NSPLIT];
  float m = -1e30f;
#pragma unroll
  for (int s = 0; s < NSPLIT; ++s) {
    ps[s] = ((size_t)(s * BB + b) * NHEADS + h) * NN + n;
    ms[s] = ml[ps[s] * 2];
    ls[s] = ml[ps[s] * 2 + 1];
    m = fmaxf(m, ms[s]);
  }
  float lsum = 0.f;
  float ws[NSPLIT];
#pragma unroll
  for (int s = 0; s < NSPLIT; ++s) {
    ws[s] = exp2f(ms[s] - m);
    lsum += ls[s] * ws[s];
  }
  float linv = 1.0f / lsum;
  float acc[4] = {0.f, 0.f, 0.f, 0.f};
#pragma unroll
  for (int s = 0; s < NSPLIT; ++s) {
    bf16x4 ov = *(const bf16x4*)&opart[ps[s] * HDIM + dq];
#pragma unroll
    for (int j = 0; j < 4; ++j) acc[j] += (float)ov[j] * ws[s];
  }
  bf16x4 pk = {(__bf16)(acc[0] * linv), (__bf16)(acc[1] * linv),
               (__bf16)(acc[2] * linv), (__bf16)(acc[3] * linv)};
  *(bf16x4*)&xa_t[((size_t)b * NN + n) * CC + h * HDIM + dq] = pk;
}

// ---------------------------------------------------------------------------
// Kernel 4: proj GEMM, reg-staged double-buffered LDS, 1 barrier per K-step,
// bias + residual(normalized x, fp32) epilogue.
// ---------------------------------------------------------------------------
__global__ __launch_bounds__(256) void proj_mfma_kernel(
    const __bf16* __restrict__ xa_t, const float* __restrict__ w,
    const float* __restrict__ bias, const float* __restrict__ x,
    const float* __restrict__ mu, const float* __restrict__ rstd,
    const float* __restrict__ lnw, const float* __restrict__ lnb,
    float* __restrict__ out) {
  __shared__ __align__(16) __bf16 As[2][64][68];
  __shared__ __align__(16) __bf16 Bs[2][64][68];
  int n0 = blockIdx.x * 64;
  int m0 = blockIdx.y * 64;
  int b = blockIdx.z;
  int tid = threadIdx.x;
  int wid = tid >> 6, lane = tid & 63;
  int g = lane >> 4, c = lane & 15;
  int wr = wid >> 1, wc = wid & 1;
  const __bf16* xab = xa_t + (size_t)b * NN * CC;
  int arow = tid >> 4, ac4 = tid & 15;
  int brow = tid >> 3, bc8 = tid & 7;

  float4 wA[4];
  bf16x8 xB[2];
  auto LOADREGS = [&](int k0) {
#pragma unroll
    for (int l = 0; l < 4; ++l)
      wA[l] = *(const float4*)&w[(size_t)(m0 + arow + 16 * l) * CC + k0 + ac4 * 4];
#pragma unroll
    for (int l = 0; l < 2; ++l)
      xB[l] = *(const bf16x8*)&xab[(size_t)(n0 + brow + 32 * l) * CC + k0 + bc8 * 8];
  };
  auto STORELDS = [&](int buf) {
#pragma unroll
    for (int l = 0; l < 4; ++l) {
      bf16x4 pk = {(__bf16)wA[l].x, (__bf16)wA[l].y, (__bf16)wA[l].z,
                   (__bf16)wA[l].w};
      *(bf16x4*)&As[buf][arow + 16 * l][ac4 * 4] = pk;
    }
#pragma unroll
    for (int l = 0; l < 2; ++l)
      *(bf16x8*)&Bs[buf][brow + 32 * l][bc8 * 8] = xB[l];
  };

  LOADREGS(0);
  STORELDS(0);
  __syncthreads();
  f32x4 acc[2][2] = {};
  for (int ktile = 0; ktile < 8; ++ktile) {
    int cur = ktile & 1;
    if (ktile < 7) LOADREGS((ktile + 1) * 64);
#pragma unroll
    for (int hh = 0; hh < 2; ++hh) {
      bf16x8 af[2], bfr[2];
#pragma unroll
      for (int mi = 0; mi < 2; ++mi)
        af[mi] = *(const bf16x8*)&As[cur][wr * 32 + mi * 16 + c][hh * 32 + g * 8];
#pragma unroll
      for (int nj = 0; nj < 2; ++nj)
        bfr[nj] = *(const bf16x8*)&Bs[cur][wc * 32 + nj * 16 + c][hh * 32 + g * 8];
#pragma unroll
      for (int mi = 0; mi < 2; ++mi)
#pragma unroll
        for (int nj = 0; nj < 2; ++nj)
          acc[mi][nj] = __builtin_amdgcn_mfma_f32_16x16x32_bf16(
              af[mi], bfr[nj], acc[mi][nj], 0, 0, 0);
    }
    if (ktile < 7) STORELDS(cur ^ 1);
    __syncthreads();
  }
#pragma unroll
  for (int mi = 0; mi < 2; ++mi)
#pragma unroll
    for (int r = 0; r < 4; ++r) {
      int o = m0 + wr * 32 + mi * 16 + 4 * g + r;
      float bo = bias[o], gw = lnw[o], gb = lnb[o];
#pragma unroll
      for (int nj = 0; nj < 2; ++nj) {
        int n = n0 + wc * 32 + nj * 16 + c;
        int tok = b * NN + n;
        float xv = x[((size_t)b * CC + o) * NN + n];
        float xlnv = (xv - mu[tok]) * rstd[tok] * gw + gb;
        out[((size_t)b * CC + o) * NN + n] = acc[mi][nj][r] + bo + xlnv;
      }
    }
}

// ---------------------------------------------------------------------------
extern "C" void kernel_launch(void* const* d_in, const int* in_sizes, int n_in,
                              void* d_out, int out_size, void* d_ws, size_t ws_size,
                              hipStream_t stream) {
  const float* x = (const float*)d_in[0];
  const float* lnw = (const float*)d_in[1];
  const float* lnb = (const float*)d_in[2];
  const float* wqkv = (const float*)d_in[3];
  const float* bqkv = (const float*)d_in[4];
  const float* wproj = (const float*)d_in[5];
  const float* bproj = (const float*)d_in[6];
  float* out = (float*)d_out;
  (void)in_sizes; (void)n_in; (void)out_size; (void)ws_size;

  char* wsb = (char*)d_ws;
  float* mu = (float*)wsb;                               // 16 KB
  float* rstd = mu + 4096;                               // 16 KB
  const size_t HSZ = (size_t)BB * NHEADS * NN * HDIM;    // 2M elems
  __bf16* qt = (__bf16*)(wsb + 32768);                   // 4 MB
  __bf16* kt = qt + HSZ;                                 // 4 MB
  __bf16* vbf = kt + HSZ;                                // 4 MB
  __bf16* xa_t = vbf + HSZ;                              // 4 MB
  __bf16* xln_t = xa_t + HSZ;                            // 4 MB (dead after qkv)
  // opart overlays xln_t's region and extends: 4 splits x 4 MB bf16 = 16 MB
  __bf16* opart = xln_t;
  float* ml = (float*)(wsb + 32768 + 4 * HSZ * sizeof(__bf16) +
                       (size_t)NSPLIT * HSZ * sizeof(__bf16));  // 1 MB

  hipLaunchKernelGGL(ln_stats_kernel, dim3(256), dim3(256), 0, stream, x, mu, rstd);
  hipLaunchKernelGGL(ln_transpose_kernel, dim3(32, 8, 2), dim3(256), 0, stream,
                     x, mu, rstd, lnw, lnb, xln_t);
  hipLaunchKernelGGL(qkv_mfma_kernel, dim3(16, 24, 2), dim3(256), 0, stream,
                     xln_t, wqkv, bqkv, qt, kt, vbf);
  hipLaunchKernelGGL(attn_mfma_kernel, dim3(16, 8, BB * NSPLIT), dim3(256), 0,
                     stream, qt, kt, vbf, opart, ml);
  hipLaunchKernelGGL(attn_combine_kernel, dim3(2048), dim3(256), 0, stream,
                     opart, ml, xa_t);
  hipLaunchKernelGGL(proj_mfma_kernel, dim3(32, 8, 2), dim3(256), 0, stream,
                     xa_t, wproj, bproj, x, mu, rstd, lnw, lnb, out);
}

// Round 13
// 79.533 us; speedup vs baseline: 1.1766x; 1.0048x over previous
//
#include <hip/hip_runtime.h>
#include <hip/hip_bf16.h>

// Problem constants
#define BB 2
#define CC 512
#define NN 2048          // T*H*W = 8*16*16
#define NHEADS 8
#define HDIM 64
#define NSPLIT 4
#define KVQ 512          // NN / NSPLIT

typedef __attribute__((ext_vector_type(8))) __bf16 bf16x8;
typedef __attribute__((ext_vector_type(4))) __bf16 bf16x4;
typedef __attribute__((ext_vector_type(2))) __bf16 bf16x2;
typedef __attribute__((ext_vector_type(4))) float f32x4;

typedef const __attribute__((address_space(1))) unsigned int guint;
typedef __attribute__((address_space(3))) unsigned int suint;

#define QSCALE 0.18033688f  // 0.125 * log2(e): QK^T lands in exp2 domain
#define MX3(a, b, c) fmaxf(fmaxf(a, b), c)

// ---------------------------------------------------------------------------
// Kernel 1: LayerNorm statistics. 256 blocks x 16 tokens.
// ---------------------------------------------------------------------------
__global__ __launch_bounds__(256) void ln_stats_kernel(
    const float* __restrict__ x, float* __restrict__ mu, float* __restrict__ rstd) {
  __shared__ float rs[16][16];
  __shared__ float rq[16][16];
  int tl = threadIdx.x & 15;   // token within block
  int cg = threadIdx.x >> 4;   // channel group (32 ch each)
  int tok = blockIdx.x * 16 + tl;
  int b = tok >> 11;
  int n = tok & (NN - 1);
  const float* xp = x + (size_t)b * CC * NN + n;
  float s = 0.f, ss = 0.f;
  int c0 = cg * 32;
#pragma unroll 8
  for (int c = c0; c < c0 + 32; ++c) {
    float v = xp[(size_t)c * NN];
    s += v;
    ss += v * v;
  }
  rs[cg][tl] = s;
  rq[cg][tl] = ss;
  __syncthreads();
  if (threadIdx.x < 16) {
    int t = threadIdx.x;
    float S = 0.f, SS = 0.f;
#pragma unroll
    for (int gidx = 0; gidx < 16; ++gidx) {
      S += rs[gidx][t];
      SS += rq[gidx][t];
    }
    float m = S * (1.0f / CC);
    float var = SS * (1.0f / CC) - m * m;
    int tk = blockIdx.x * 16 + t;
    mu[tk] = m;
    rstd[tk] = rsqrtf(var + 1e-5f);
  }
}

// ---------------------------------------------------------------------------
// Kernel 1b: LN apply + transpose: x[b][c][n] fp32 -> xln_t[b][n][c] bf16.
// ---------------------------------------------------------------------------
__global__ __launch_bounds__(256) void ln_transpose_kernel(
    const float* __restrict__ x, const float* __restrict__ mu,
    const float* __restrict__ rstd, const float* __restrict__ lnw,
    const float* __restrict__ lnb, __bf16* __restrict__ xln_t) {
  __shared__ float Xs[64][68];
  int n0 = blockIdx.x * 64;
  int c0 = blockIdx.y * 64;
  int b = blockIdx.z;
  int tid = threadIdx.x;
#pragma unroll
  for (int l = 0; l < 4; ++l) {
    int e = tid + 256 * l;
    int row = e >> 4, c4 = e & 15;
    float4 v = *(const float4*)&x[((size_t)b * CC + c0 + row) * NN + n0 + c4 * 4];
    *(float4*)&Xs[row][c4 * 4] = v;
  }
  __syncthreads();
  int sr = tid >> 2;
  int sc = (tid & 3) * 16;
  int tok = b * NN + n0 + sr;
  float mun = mu[tok], rsn = rstd[tok];
  __bf16 outv[16];
#pragma unroll
  for (int j = 0; j < 16; ++j) {
    int c = c0 + sc + j;
    outv[j] = (__bf16)((Xs[sc + j][sr] - mun) * rsn * lnw[c] + lnb[c]);
  }
  __bf16* dst = &xln_t[((size_t)b * NN + n0 + sr) * CC + c0 + sc];
  *(bf16x8*)&dst[0] = *(bf16x8*)&outv[0];
  *(bf16x8*)&dst[8] = *(bf16x8*)&outv[8];
}

// ---------------------------------------------------------------------------
// Kernel 2: merged QKV GEMM, bf16 MFMA, reg-staged double-buffered LDS,
// ONE barrier per K-step. blockIdx.y<16 -> q/k (swapped mfma, [n][d] out);
// else -> v ([c][n] out).
// ---------------------------------------------------------------------------
__global__ __launch_bounds__(256) void qkv_mfma_kernel(
    const __bf16* __restrict__ xln_t, const float* __restrict__ w,
    const float* __restrict__ bias, __bf16* __restrict__ qt,
    __bf16* __restrict__ kt, __bf16* __restrict__ vbf) {
  __shared__ __align__(16) __bf16 As[2][64][68];   // 17.0 KiB
  __shared__ __align__(16) __bf16 Bs[2][128][68];  // 34.0 KiB
  int n0 = blockIdx.x * 128;
  bool swap = blockIdx.y < 16;
  int m0 = swap ? blockIdx.y * 64 : 1024 + ((int)blockIdx.y - 16) * 64;
  int b = blockIdx.z;
  int tid = threadIdx.x;
  int wid = tid >> 6, lane = tid & 63;
  int g = lane >> 4, c = lane & 15;
  int wr = wid >> 1, wc = wid & 1;
  const __bf16* xln = xln_t + (size_t)b * NN * CC;
  int arow = tid >> 4, ac4 = tid & 15;
  int brow = tid >> 3, bc8 = tid & 7;

  float4 wA[4];
  bf16x8 xB[4];
  auto LOADREGS = [&](int k0) {
#pragma unroll
    for (int l = 0; l < 4; ++l)
      wA[l] = *(const float4*)&w[(size_t)(m0 + arow + 16 * l) * CC + k0 + ac4 * 4];
#pragma unroll
    for (int l = 0; l < 4; ++l)
      xB[l] = *(const bf16x8*)&xln[(size_t)(n0 + brow + 32 * l) * CC + k0 + bc8 * 8];
  };
  auto STORELDS = [&](int buf) {
#pragma unroll
    for (int l = 0; l < 4; ++l) {
      bf16x4 pk = {(__bf16)wA[l].x, (__bf16)wA[l].y, (__bf16)wA[l].z,
                   (__bf16)wA[l].w};
      *(bf16x4*)&As[buf][arow + 16 * l][ac4 * 4] = pk;
    }
#pragma unroll
    for (int l = 0; l < 4; ++l)
      *(bf16x8*)&Bs[buf][brow + 32 * l][bc8 * 8] = xB[l];
  };

  LOADREGS(0);
  STORELDS(0);
  __syncthreads();
  f32x4 acc[2][4] = {};
  for (int ktile = 0; ktile < 8; ++ktile) {
    int cur = ktile & 1;
    if (ktile < 7) LOADREGS((ktile + 1) * 64);
#pragma unroll
    for (int hh = 0; hh < 2; ++hh) {
      bf16x8 af[2], bfr[4];
#pragma unroll
      for (int mi = 0; mi < 2; ++mi)
        af[mi] = *(const bf16x8*)&As[cur][wr * 32 + mi * 16 + c][hh * 32 + g * 8];
#pragma unroll
      for (int nj = 0; nj < 4; ++nj)
        bfr[nj] = *(const bf16x8*)&Bs[cur][wc * 64 + nj * 16 + c][hh * 32 + g * 8];
      if (swap) {
#pragma unroll
        for (int mi = 0; mi < 2; ++mi)
#pragma unroll
          for (int nj = 0; nj < 4; ++nj)
            acc[mi][nj] = __builtin_amdgcn_mfma_f32_16x16x32_bf16(
                bfr[nj], af[mi], acc[mi][nj], 0, 0, 0);
      } else {
#pragma unroll
        for (int mi = 0; mi < 2; ++mi)
#pragma unroll
          for (int nj = 0; nj < 4; ++nj)
            acc[mi][nj] = __builtin_amdgcn_mfma_f32_16x16x32_bf16(
                af[mi], bfr[nj], acc[mi][nj], 0, 0, 0);
      }
    }
    if (ktile < 7) STORELDS(cur ^ 1);
    __syncthreads();
  }
  if (swap) {
    int obase = m0 + wr * 32;
    int sec = obase >> 9;  // 0=q, 1=k
    int osec = obase & 511;
    int head = osec >> 6;
    int dbase = osec & 63;
    __bf16* dst = (sec == 0 ? qt : kt) + (size_t)(b * NHEADS + head) * NN * HDIM;
    float scl = (sec == 0) ? QSCALE : 1.0f;
#pragma unroll
    for (int mi = 0; mi < 2; ++mi) {
      float bo = bias[obase + mi * 16 + c];
      int d = dbase + mi * 16 + c;
#pragma unroll
      for (int nj = 0; nj < 4; ++nj)
#pragma unroll
        for (int r = 0; r < 4; ++r) {
          int n = n0 + wc * 64 + nj * 16 + 4 * g + r;
          dst[(size_t)n * HDIM + d] = (__bf16)((acc[mi][nj][r] + bo) * scl);
        }
    }
  } else {
#pragma unroll
    for (int mi = 0; mi < 2; ++mi)
#pragma unroll
      for (int r = 0; r < 4; ++r) {
        int o = m0 + wr * 32 + mi * 16 + 4 * g + r;
        int ch = o - 1024;
        float bo = bias[o];
#pragma unroll
        for (int nj = 0; nj < 4; ++nj) {
          int n = n0 + wc * 64 + nj * 16 + c;
          vbf[((size_t)b * CC + ch) * NN + n] = (__bf16)(acc[mi][nj][r] + bo);
        }
      }
  }
}

// ---------------------------------------------------------------------------
// Kernel 3: flash attention, split-KV x4, 4 waves x 256 thr, QBLK=128,
// 2 q-groups per wave, R12 softmax (lane-local defer, ones-MFMA l, max3).
// NEW: counted-vmcnt double buffer (T4) — raw s_barrier + s_waitcnt vmcnt(4)
// so the next-tile global_load_lds prefetch stays in flight across the
// barrier instead of being drained to 0 by __syncthreads every iteration.
// ---------------------------------------------------------------------------
__global__ __launch_bounds__(256, 3) void attn_mfma_kernel(
    const __bf16* __restrict__ qt, const __bf16* __restrict__ ktg,
    const __bf16* __restrict__ vbf, __bf16* __restrict__ opart,
    float* __restrict__ ml) {
  __shared__ __align__(16) __bf16 Kb[2][64][64];  // 16 KiB
  __shared__ __align__(16) __bf16 Vb[2][64][64];  // 16 KiB
  int tid = threadIdx.x;
  int wid = tid >> 6, lane = tid & 63;
  int g = lane >> 4, c = lane & 15;
  int n0 = blockIdx.x * 128;
  int h = blockIdx.y;
  int b = blockIdx.z >> 2, split = blockIdx.z & 3;
  int bh = b * NHEADS + h;
  const __bf16* qbase = qt + ((size_t)bh * NN + n0) * HDIM;
  const __bf16* kbase = ktg + ((size_t)bh * NN + split * KVQ) * HDIM;
  const __bf16* vbase = vbf + ((size_t)b * CC + h * HDIM) * NN + split * KVQ;

  int l7 = lane & 7, l3 = lane >> 3;  // dest chunk, row-within-8
  int xr = (l7 ^ l3) * 8;             // XOR-swizzled source chunk (elements)
  auto STAGE = [&](int buf, int mt) {
#pragma unroll
    for (int j = 0; j < 2; ++j) {
      int r = wid * 16 + 8 * j + l3;  // dest row; r&7 == l3
      // K: dest row r holds logical K row inv(r) (inverse of the PV-layout
      // permutation p(i) = (i>>5)<<5 | ((i>>2)&1)<<4 | ((i>>3)&3)<<2 | (i&3))
      int gr = (r & 0x20) | (((r >> 2) & 3) << 3) | (((r >> 4) & 1) << 2) | (r & 3);
      const __bf16* ksrc = kbase + (size_t)(mt + gr) * HDIM + xr;
      __builtin_amdgcn_global_load_lds((guint*)ksrc,
                                       (suint*)&Kb[buf][wid * 16 + 8 * j][0],
                                       16, 0, 0);
      const __bf16* vsrc = vbase + (size_t)r * NN + mt + xr;
      __builtin_amdgcn_global_load_lds((guint*)vsrc,
                                       (suint*)&Vb[buf][wid * 16 + 8 * j][0],
                                       16, 0, 0);
    }
  };

  STAGE(0, 0);   // 4 loads in flight for buffer 0
  // Q fragments for both q-groups (held in regs for the whole kernel)
  bf16x8 aq[2][2];
#pragma unroll
  for (int qg = 0; qg < 2; ++qg) {
    const __bf16* qp = qbase + (size_t)(wid * 32 + qg * 16 + c) * HDIM;
    aq[qg][0] = *(const bf16x8*)(qp + g * 8);
    aq[qg][1] = *(const bf16x8*)(qp + 32 + g * 8);
  }
  f32x4 O[2][4] = {};   // O^T per qg: O[qg][dt][r] = O^T[d=dt*16+4g+r][q=c]
  f32x4 Ol[2] = {};     // ones-row accumulator: Ol[qg][*] = l for q-row c
  float m_[2] = {-1e30f, -1e30f};
  int cxor = (c & 7);   // read-side XOR (row&7 == c&7 for rows t4*16+c)
  const bf16x8 vones = {(__bf16)1.f, (__bf16)1.f, (__bf16)1.f, (__bf16)1.f,
                        (__bf16)1.f, (__bf16)1.f, (__bf16)1.f, (__bf16)1.f};

  for (int t = 0; t < KVQ / 64; ++t) {
    int cur = t & 1;
    if (t + 1 < KVQ / 64) {
      STAGE(cur ^ 1, (t + 1) * 64);  // prefetch stays in flight across barrier
      asm volatile("s_waitcnt vmcnt(4)" ::: "memory");  // buf[cur]'s 4 landed
    } else {
      asm volatile("s_waitcnt vmcnt(0)" ::: "memory");
    }
    __builtin_amdgcn_sched_barrier(0);
    __builtin_amdgcn_s_barrier();  // all waves: buf[cur] fully written
    // ---- QK^T swapped: st[qg][t4][r] = S[q=c][k] ----
    f32x4 st[2][4];
    __builtin_amdgcn_s_setprio(1);
#pragma unroll
    for (int t4 = 0; t4 < 4; ++t4) {
      bf16x8 bk0 = *(const bf16x8*)&Kb[cur][t4 * 16 + c][(g ^ cxor) * 8];
      bf16x8 bk1 = *(const bf16x8*)&Kb[cur][t4 * 16 + c][((4 + g) ^ cxor) * 8];
#pragma unroll
      for (int qg = 0; qg < 2; ++qg) {
        f32x4 acc = {0.f, 0.f, 0.f, 0.f};
        acc = __builtin_amdgcn_mfma_f32_16x16x32_bf16(bk0, aq[qg][0], acc, 0, 0, 0);
        acc = __builtin_amdgcn_mfma_f32_16x16x32_bf16(bk1, aq[qg][1], acc, 0, 0, 0);
        st[qg][t4] = acc;
      }
    }
    __builtin_amdgcn_s_setprio(0);
    // ---- softmax: lane-local max3 tree + defer-rescale (no hot shuffles) ----
    bf16x8 pa[2][2];
#pragma unroll
    for (int qg = 0; qg < 2; ++qg) {
      float g0 = MX3(st[qg][0][0], st[qg][0][1], st[qg][0][2]);
      float g1 = MX3(st[qg][0][3], st[qg][1][0], st[qg][1][1]);
      float g2 = MX3(st[qg][1][2], st[qg][1][3], st[qg][2][0]);
      float g3 = MX3(st[qg][2][1], st[qg][2][2], st[qg][2][3]);
      float g4 = MX3(st[qg][3][0], st[qg][3][1], st[qg][3][2]);
      float pm = fmaxf(MX3(g0, g1, g2), MX3(g3, g4, st[qg][3][3]));
      if (!__all(pm <= m_[qg] + 8.0f)) {  // rare: first iter + occasional
        float rm = fmaxf(pm, __shfl_xor(pm, 16));
        rm = fmaxf(rm, __shfl_xor(rm, 32));
        float mn = fmaxf(m_[qg], rm);
        float fs = exp2f(m_[qg] - mn);
        m_[qg] = mn;
#pragma unroll
        for (int dt = 0; dt < 4; ++dt)
#pragma unroll
          for (int r = 0; r < 4; ++r) O[qg][dt][r] *= fs;
#pragma unroll
        for (int r = 0; r < 4; ++r) Ol[qg][r] *= fs;
      }
#pragma unroll
      for (int t4 = 0; t4 < 4; ++t4) {
        float p0 = exp2f(st[qg][t4][0] - m_[qg]);
        float p1 = exp2f(st[qg][t4][1] - m_[qg]);
        float p2 = exp2f(st[qg][t4][2] - m_[qg]);
        float p3 = exp2f(st[qg][t4][3] - m_[qg]);
        bf16x8* pp = &pa[qg][t4 >> 1];
        int o4 = (t4 & 1) * 4;
        (*pp)[o4 + 0] = (__bf16)p0;
        (*pp)[o4 + 1] = (__bf16)p1;
        (*pp)[o4 + 2] = (__bf16)p2;
        (*pp)[o4 + 3] = (__bf16)p3;
      }
    }
    // ---- PV swapped + ones-row l (each V fragment feeds both q-groups) ----
    __builtin_amdgcn_s_setprio(1);
#pragma unroll
    for (int dt = 0; dt < 4; ++dt) {
      bf16x8 bv0 = *(const bf16x8*)&Vb[cur][dt * 16 + c][(g ^ cxor) * 8];
      bf16x8 bv1 = *(const bf16x8*)&Vb[cur][dt * 16 + c][((4 + g) ^ cxor) * 8];
#pragma unroll
      for (int qg = 0; qg < 2; ++qg) {
        O[qg][dt] = __builtin_amdgcn_mfma_f32_16x16x32_bf16(bv0, pa[qg][0],
                                                            O[qg][dt], 0, 0, 0);
        O[qg][dt] = __builtin_amdgcn_mfma_f32_16x16x32_bf16(bv1, pa[qg][1],
                                                            O[qg][dt], 0, 0, 0);
      }
    }
#pragma unroll
    for (int qg = 0; qg < 2; ++qg) {
      Ol[qg] = __builtin_amdgcn_mfma_f32_16x16x32_bf16(vones, pa[qg][0],
                                                       Ol[qg], 0, 0, 0);
      Ol[qg] = __builtin_amdgcn_mfma_f32_16x16x32_bf16(vones, pa[qg][1],
                                                       Ol[qg], 0, 0, 0);
    }
    __builtin_amdgcn_s_setprio(0);
    __builtin_amdgcn_s_barrier();  // all waves done READING buf[cur] before
                                   // next iter's STAGE overwrites it
  }
  // ---- epilogue: unnormalized bf16 partials + (m, l) per q-group ----
#pragma unroll
  for (int qg = 0; qg < 2; ++qg) {
    size_t prow = ((size_t)(split * BB + b) * NHEADS + h) * NN +
                  (n0 + wid * 32 + qg * 16 + c);
#pragma unroll
    for (int dt = 0; dt < 4; ++dt) {
      bf16x4 pk = {(__bf16)O[qg][dt][0], (__bf16)O[qg][dt][1],
                   (__bf16)O[qg][dt][2], (__bf16)O[qg][dt][3]};
      *(bf16x4*)&opart[prow * HDIM + dt * 16 + 4 * g] = pk;
    }
    if (lane < 16) {
      float2 mlv = {m_[qg], Ol[qg][0]};
      *(float2*)&ml[prow * 2] = mlv;
    }
  }
}

// ---------------------------------------------------------------------------
// Kernel 3b: combine the four KV-split partials -> xa_t[b][n][c] bf16.
// ---------------------------------------------------------------------------
__global__ __launch_bounds__(256) void attn_combine_kernel(
    const __bf16* __restrict__ opart, const float* __restrict__ ml,
    __bf16* __restrict__ xa_t) {
  int t = threadIdx.x;
  int row_local = t >> 4;          // 0..15
  int dq = (t & 15) * 4;           // 0..60
  int R = blockIdx.x * 16 + row_local;  // global (b,h,n) row, 0..32767
  int n = R & (NN - 1);
  int bh = R >> 11;
  int b = bh >> 3, h = bh & 7;
  size_t ps[NSPLIT];
  float ms[NSPLIT], ls[NSPLIT];
  float m = -1e30f;
#pragma unroll
  for (int s = 0; s < NSPLIT; ++s) {
    ps[s] = ((size_t)(s * BB + b) * NHEADS + h) * NN + n;
    ms[s] = ml[ps[s] * 2];
    ls[s] = ml[ps[s] * 2 + 1];
    m = fmaxf(m, ms[s]);
  }
  float lsum = 0.f;
  float ws[NSPLIT];
#pragma unroll
  for (int s = 0; s < NSPLIT; ++s) {
    ws[s] = exp2f(ms[s] - m);
    lsum += ls[s] * ws[s];
  }
  float linv = 1.0f / lsum;
  float acc[4] = {0.f, 0.f, 0.f, 0.f};
#pragma unroll
  for (int s = 0; s < NSPLIT; ++s) {
    bf16x4 ov = *(const bf16x4*)&opart[ps[s] * HDIM + dq];
#pragma unroll
    for (int j = 0; j < 4; ++j) acc[j] += (float)ov[j] * ws[s];
  }
  bf16x4 pk = {(__bf16)(acc[0] * linv), (__bf16)(acc[1] * linv),
               (__bf16)(acc[2] * linv), (__bf16)(acc[3] * linv)};
  *(bf16x4*)&xa_t[((size_t)b * NN + n) * CC + h * HDIM + dq] = pk;
}

// ---------------------------------------------------------------------------
// Kernel 4: proj GEMM, reg-staged double-buffered LDS, 1 barrier per K-step,
// bias + residual(normalized x, fp32) epilogue.
// ---------------------------------------------------------------------------
__global__ __launch_bounds__(256) void proj_mfma_kernel(
    const __bf16* __restrict__ xa_t, const float* __restrict__ w,
    const float* __restrict__ bias, const float* __restrict__ x,
    const float* __restrict__ mu, const float* __restrict__ rstd,
    const float* __restrict__ lnw, const float* __restrict__ lnb,
    float* __restrict__ out) {
  __shared__ __align__(16) __bf16 As[2][64][68];
  __shared__ __align__(16) __bf16 Bs[2][64][68];
  int n0 = blockIdx.x * 64;
  int m0 = blockIdx.y * 64;
  int b = blockIdx.z;
  int tid = threadIdx.x;
  int wid = tid >> 6, lane = tid & 63;
  int g = lane >> 4, c = lane & 15;
  int wr = wid >> 1, wc = wid & 1;
  const __bf16* xab = xa_t + (size_t)b * NN * CC;
  int arow = tid >> 4, ac4 = tid & 15;
  int brow = tid >> 3, bc8 = tid & 7;

  float4 wA[4];
  bf16x8 xB[2];
  auto LOADREGS = [&](int k0) {
#pragma unroll
    for (int l = 0; l < 4; ++l)
      wA[l] = *(const float4*)&w[(size_t)(m0 + arow + 16 * l) * CC + k0 + ac4 * 4];
#pragma unroll
    for (int l = 0; l < 2; ++l)
      xB[l] = *(const bf16x8*)&xab[(size_t)(n0 + brow + 32 * l) * CC + k0 + bc8 * 8];
  };
  auto STORELDS = [&](int buf) {
#pragma unroll
    for (int l = 0; l < 4; ++l) {
      bf16x4 pk = {(__bf16)wA[l].x, (__bf16)wA[l].y, (__bf16)wA[l].z,
                   (__bf16)wA[l].w};
      *(bf16x4*)&As[buf][arow + 16 * l][ac4 * 4] = pk;
    }
#pragma unroll
    for (int l = 0; l < 2; ++l)
      *(bf16x8*)&Bs[buf][brow + 32 * l][bc8 * 8] = xB[l];
  };

  LOADREGS(0);
  STORELDS(0);
  __syncthreads();
  f32x4 acc[2][2] = {};
  for (int ktile = 0; ktile < 8; ++ktile) {
    int cur = ktile & 1;
    if (ktile < 7) LOADREGS((ktile + 1) * 64);
#pragma unroll
    for (int hh = 0; hh < 2; ++hh) {
      bf16x8 af[2], bfr[2];
#pragma unroll
      for (int mi = 0; mi < 2; ++mi)
        af[mi] = *(const bf16x8*)&As[cur][wr * 32 + mi * 16 + c][hh * 32 + g * 8];
#pragma unroll
      for (int nj = 0; nj < 2; ++nj)
        bfr[nj] = *(const bf16x8*)&Bs[cur][wc * 32 + nj * 16 + c][hh * 32 + g * 8];
#pragma unroll
      for (int mi = 0; mi < 2; ++mi)
#pragma unroll
        for (int nj = 0; nj < 2; ++nj)
          acc[mi][nj] = __builtin_amdgcn_mfma_f32_16x16x32_bf16(
              af[mi], bfr[nj], acc[mi][nj], 0, 0, 0);
    }
    if (ktile < 7) STORELDS(cur ^ 1);
    __syncthreads();
  }
#pragma unroll
  for (int mi = 0; mi < 2; ++mi)
#pragma unroll
    for (int r = 0; r < 4; ++r) {
      int o = m0 + wr * 32 + mi * 16 + 4 * g + r;
      float bo = bias[o], gw = lnw[o], gb = lnb[o];
#pragma unroll
      for (int nj = 0; nj < 2; ++nj) {
        int n = n0 + wc * 32 + nj * 16 + c;
        int tok = b * NN + n;
        float xv = x[((size_t)b * CC + o) * NN + n];
        float xlnv = (xv - mu[tok]) * rstd[tok] * gw + gb;
        out[((size_t)b * CC + o) * NN + n] = acc[mi][nj][r] + bo + xlnv;
      }
    }
}

// ---------------------------------------------------------------------------
extern "C" void kernel_launch(void* const* d_in, const int* in_sizes, int n_in,
                              void* d_out, int out_size, void* d_ws, size_t ws_size,
                              hipStream_t stream) {
  const float* x = (const float*)d_in[0];
  const float* lnw = (const float*)d_in[1];
  const float* lnb = (const float*)d_in[2];
  const float* wqkv = (const float*)d_in[3];
  const float* bqkv = (const float*)d_in[4];
  const float* wproj = (const float*)d_in[5];
  const float* bproj = (const float*)d_in[6];
  float* out = (float*)d_out;
  (void)in_sizes; (void)n_in; (void)out_size; (void)ws_size;

  char* wsb = (char*)d_ws;
  float* mu = (float*)wsb;                               // 16 KB
  float* rstd = mu + 4096;                               // 16 KB
  const size_t HSZ = (size_t)BB * NHEADS * NN * HDIM;    // 2M elems
  __bf16* qt = (__bf16*)(wsb + 32768);                   // 4 MB
  __bf16* kt = qt + HSZ;                                 // 4 MB
  __bf16* vbf = kt + HSZ;                                // 4 MB
  __bf16* xa_t = vbf + HSZ;                              // 4 MB
  __bf16* xln_t = xa_t + HSZ;                            // 4 MB (dead after qkv)
  // opart overlays xln_t's region and extends: 4 splits x 4 MB bf16 = 16 MB
  __bf16* opart = xln_t;
  float* ml = (float*)(wsb + 32768 + 4 * HSZ * sizeof(__bf16) +
                       (size_t)NSPLIT * HSZ * sizeof(__bf16));  // 1 MB

  hipLaunchKernelGGL(ln_stats_kernel, dim3(256), dim3(256), 0, stream, x, mu, rstd);
  hipLaunchKernelGGL(ln_transpose_kernel, dim3(32, 8, 2), dim3(256), 0, stream,
                     x, mu, rstd, lnw, lnb, xln_t);
  hipLaunchKernelGGL(qkv_mfma_kernel, dim3(16, 24, 2), dim3(256), 0, stream,
                     xln_t, wqkv, bqkv, qt, kt, vbf);
  hipLaunchKernelGGL(attn_mfma_kernel, dim3(16, 8, BB * NSPLIT), dim3(256), 0,
                     stream, qt, kt, vbf, opart, ml);
  hipLaunchKernelGGL(attn_combine_kernel, dim3(2048), dim3(256), 0, stream,
                     opart, ml, xa_t);
  hipLaunchKernelGGL(proj_mfma_kernel, dim3(32, 8, 2), dim3(256), 0, stream,
                     xa_t, wproj, bproj, x, mu, rstd, lnw, lnb, out);
}

// Round 14
// 77.529 us; speedup vs baseline: 1.2070x; 1.0258x over previous
//
#include <hip/hip_runtime.h>
#include <hip/hip_bf16.h>

// Problem constants
#define BB 2
#define CC 512
#define NN 2048          // T*H*W = 8*16*16
#define NHEADS 8
#define HDIM 64
#define NSPLIT 4
#define KVQ 512          // NN / NSPLIT

typedef __attribute__((ext_vector_type(8))) __bf16 bf16x8;
typedef __attribute__((ext_vector_type(4))) __bf16 bf16x4;
typedef __attribute__((ext_vector_type(2))) __bf16 bf16x2;
typedef __attribute__((ext_vector_type(4))) float f32x4;

typedef const __attribute__((address_space(1))) unsigned int guint;
typedef __attribute__((address_space(3))) unsigned int suint;

#define QSCALE 0.18033688f  // 0.125 * log2(e): QK^T lands in exp2 domain
#define MX3(a, b, c) fmaxf(fmaxf(a, b), c)

// ---------------------------------------------------------------------------
// Kernel 1 (FUSED): LayerNorm stats + apply + transpose in ONE pass over x.
// Block = 16 tokens x 512 channels staged in LDS (stride 20 floats -> 16B
// aligned float4 rows). Writes xln_t[b][n][c] bf16 and mu/rstd (for proj).
// blockIdx pair-swizzle: blocks handling n-tiles 2k/2k+1 (which share 128B
// cache lines) land on the same XCD under round-robin dispatch -> L2 serves
// the second half-line; HBM stays at the compulsory 33 MB.
// ---------------------------------------------------------------------------
__global__ __launch_bounds__(256) void ln_fused_kernel(
    const float* __restrict__ x, const float* __restrict__ lnw,
    const float* __restrict__ lnb, float* __restrict__ mu,
    float* __restrict__ rstd, __bf16* __restrict__ xln_t) {
  __shared__ float Xs[512][20];   // 40 KiB; stride 20 floats = 80B (16B-align)
  __shared__ float rs[16][17];
  __shared__ float rq[16][17];
  __shared__ float mloc[16];
  __shared__ float rloc[16];
  int bid = blockIdx.x;           // [0,128)
  // pair-swizzle: bid = (hi<<4)|(m<<3)|lo -> n_tile = 16*hi + 2*lo + m
  int n_tile = 2 * (((bid >> 4) << 3) + (bid & 7)) + ((bid >> 3) & 1);
  int n0 = n_tile * 16;
  int b = blockIdx.y;
  int tid = threadIdx.x;
  // ---- phase 1: load 512x16 fp32 tile (x is [b][c][n], coalesced on n) ----
#pragma unroll
  for (int l = 0; l < 8; ++l) {
    int e = tid + 256 * l;
    int row = e >> 2, quad = e & 3;
    float4 v = *(const float4*)&x[((size_t)b * CC + row) * NN + n0 + quad * 4];
    *(float4*)&Xs[row][quad * 4] = v;
  }
  __syncthreads();
  // ---- phase 2: stats. 16 threads per token, 32 channels each ----
  {
    int tk = tid & 15, part = tid >> 4;
    float s = 0.f, ss = 0.f;
    int c0 = part * 32;
#pragma unroll 8
    for (int j = 0; j < 32; ++j) {
      float v = Xs[c0 + j][tk];
      s += v;
      ss += v * v;
    }
    rs[part][tk] = s;
    rq[part][tk] = ss;
  }
  __syncthreads();
  if (tid < 16) {
    float S = 0.f, SS = 0.f;
#pragma unroll
    for (int p = 0; p < 16; ++p) {
      S += rs[p][tid];
      SS += rq[p][tid];
    }
    float m = S * (1.0f / CC);
    float var = SS * (1.0f / CC) - m * m;
    float rv = rsqrtf(var + 1e-5f);
    mloc[tid] = m;
    rloc[tid] = rv;
    int tok = b * NN + n0 + tid;
    mu[tok] = m;
    rstd[tok] = rv;
  }
  __syncthreads();
  // ---- phase 3: apply LN + write transposed bf16 (coalesced on c) ----
  {
    int tk = tid >> 4;            // token 0..15
    int cseg = (tid & 15) * 32;   // 32-channel segment
    float mun = mloc[tk], rsn = rloc[tk];
    __bf16 outv[32];
#pragma unroll
    for (int j = 0; j < 32; ++j) {
      int c = cseg + j;
      outv[j] = (__bf16)((Xs[c][tk] - mun) * rsn * lnw[c] + lnb[c]);
    }
    __bf16* dst = &xln_t[((size_t)b * NN + n0 + tk) * CC + cseg];
#pragma unroll
    for (int q = 0; q < 4; ++q) *(bf16x8*)&dst[q * 8] = *(bf16x8*)&outv[q * 8];
  }
}

// ---------------------------------------------------------------------------
// Kernel 2: merged QKV GEMM, bf16 MFMA, reg-staged double-buffered LDS,
// ONE barrier per K-step. blockIdx.y<16 -> q/k (swapped mfma, [n][d] out);
// else -> v ([c][n] out).
// ---------------------------------------------------------------------------
__global__ __launch_bounds__(256) void qkv_mfma_kernel(
    const __bf16* __restrict__ xln_t, const float* __restrict__ w,
    const float* __restrict__ bias, __bf16* __restrict__ qt,
    __bf16* __restrict__ kt, __bf16* __restrict__ vbf) {
  __shared__ __align__(16) __bf16 As[2][64][68];   // 17.0 KiB
  __shared__ __align__(16) __bf16 Bs[2][128][68];  // 34.0 KiB
  int n0 = blockIdx.x * 128;
  bool swap = blockIdx.y < 16;
  int m0 = swap ? blockIdx.y * 64 : 1024 + ((int)blockIdx.y - 16) * 64;
  int b = blockIdx.z;
  int tid = threadIdx.x;
  int wid = tid >> 6, lane = tid & 63;
  int g = lane >> 4, c = lane & 15;
  int wr = wid >> 1, wc = wid & 1;
  const __bf16* xln = xln_t + (size_t)b * NN * CC;
  int arow = tid >> 4, ac4 = tid & 15;
  int brow = tid >> 3, bc8 = tid & 7;

  float4 wA[4];
  bf16x8 xB[4];
  auto LOADREGS = [&](int k0) {
#pragma unroll
    for (int l = 0; l < 4; ++l)
      wA[l] = *(const float4*)&w[(size_t)(m0 + arow + 16 * l) * CC + k0 + ac4 * 4];
#pragma unroll
    for (int l = 0; l < 4; ++l)
      xB[l] = *(const bf16x8*)&xln[(size_t)(n0 + brow + 32 * l) * CC + k0 + bc8 * 8];
  };
  auto STORELDS = [&](int buf) {
#pragma unroll
    for (int l = 0; l < 4; ++l) {
      bf16x4 pk = {(__bf16)wA[l].x, (__bf16)wA[l].y, (__bf16)wA[l].z,
                   (__bf16)wA[l].w};
      *(bf16x4*)&As[buf][arow + 16 * l][ac4 * 4] = pk;
    }
#pragma unroll
    for (int l = 0; l < 4; ++l)
      *(bf16x8*)&Bs[buf][brow + 32 * l][bc8 * 8] = xB[l];
  };

  LOADREGS(0);
  STORELDS(0);
  __syncthreads();
  f32x4 acc[2][4] = {};
  for (int ktile = 0; ktile < 8; ++ktile) {
    int cur = ktile & 1;
    if (ktile < 7) LOADREGS((ktile + 1) * 64);
#pragma unroll
    for (int hh = 0; hh < 2; ++hh) {
      bf16x8 af[2], bfr[4];
#pragma unroll
      for (int mi = 0; mi < 2; ++mi)
        af[mi] = *(const bf16x8*)&As[cur][wr * 32 + mi * 16 + c][hh * 32 + g * 8];
#pragma unroll
      for (int nj = 0; nj < 4; ++nj)
        bfr[nj] = *(const bf16x8*)&Bs[cur][wc * 64 + nj * 16 + c][hh * 32 + g * 8];
      if (swap) {
#pragma unroll
        for (int mi = 0; mi < 2; ++mi)
#pragma unroll
          for (int nj = 0; nj < 4; ++nj)
            acc[mi][nj] = __builtin_amdgcn_mfma_f32_16x16x32_bf16(
                bfr[nj], af[mi], acc[mi][nj], 0, 0, 0);
      } else {
#pragma unroll
        for (int mi = 0; mi < 2; ++mi)
#pragma unroll
          for (int nj = 0; nj < 4; ++nj)
            acc[mi][nj] = __builtin_amdgcn_mfma_f32_16x16x32_bf16(
                af[mi], bfr[nj], acc[mi][nj], 0, 0, 0);
      }
    }
    if (ktile < 7) STORELDS(cur ^ 1);
    __syncthreads();
  }
  if (swap) {
    int obase = m0 + wr * 32;
    int sec = obase >> 9;  // 0=q, 1=k
    int osec = obase & 511;
    int head = osec >> 6;
    int dbase = osec & 63;
    __bf16* dst = (sec == 0 ? qt : kt) + (size_t)(b * NHEADS + head) * NN * HDIM;
    float scl = (sec == 0) ? QSCALE : 1.0f;
#pragma unroll
    for (int mi = 0; mi < 2; ++mi) {
      float bo = bias[obase + mi * 16 + c];
      int d = dbase + mi * 16 + c;
#pragma unroll
      for (int nj = 0; nj < 4; ++nj)
#pragma unroll
        for (int r = 0; r < 4; ++r) {
          int n = n0 + wc * 64 + nj * 16 + 4 * g + r;
          dst[(size_t)n * HDIM + d] = (__bf16)((acc[mi][nj][r] + bo) * scl);
        }
    }
  } else {
#pragma unroll
    for (int mi = 0; mi < 2; ++mi)
#pragma unroll
      for (int r = 0; r < 4; ++r) {
        int o = m0 + wr * 32 + mi * 16 + 4 * g + r;
        int ch = o - 1024;
        float bo = bias[o];
#pragma unroll
        for (int nj = 0; nj < 4; ++nj) {
          int n = n0 + wc * 64 + nj * 16 + c;
          vbf[((size_t)b * CC + ch) * NN + n] = (__bf16)(acc[mi][nj][r] + bo);
        }
      }
  }
}

// ---------------------------------------------------------------------------
// Kernel 3: flash attention, split-KV x4, 4 waves x 256 thr, QBLK=128,
// 2 q-groups per wave, lane-local defer softmax, ones-MFMA l, max3 tree,
// counted-vmcnt double buffer (R13 structure, unchanged).
// ---------------------------------------------------------------------------
__global__ __launch_bounds__(256, 3) void attn_mfma_kernel(
    const __bf16* __restrict__ qt, const __bf16* __restrict__ ktg,
    const __bf16* __restrict__ vbf, __bf16* __restrict__ opart,
    float* __restrict__ ml) {
  __shared__ __align__(16) __bf16 Kb[2][64][64];  // 16 KiB
  __shared__ __align__(16) __bf16 Vb[2][64][64];  // 16 KiB
  int tid = threadIdx.x;
  int wid = tid >> 6, lane = tid & 63;
  int g = lane >> 4, c = lane & 15;
  int n0 = blockIdx.x * 128;
  int h = blockIdx.y;
  int b = blockIdx.z >> 2, split = blockIdx.z & 3;
  int bh = b * NHEADS + h;
  const __bf16* qbase = qt + ((size_t)bh * NN + n0) * HDIM;
  const __bf16* kbase = ktg + ((size_t)bh * NN + split * KVQ) * HDIM;
  const __bf16* vbase = vbf + ((size_t)b * CC + h * HDIM) * NN + split * KVQ;

  int l7 = lane & 7, l3 = lane >> 3;  // dest chunk, row-within-8
  int xr = (l7 ^ l3) * 8;             // XOR-swizzled source chunk (elements)
  auto STAGE = [&](int buf, int mt) {
#pragma unroll
    for (int j = 0; j < 2; ++j) {
      int r = wid * 16 + 8 * j + l3;  // dest row; r&7 == l3
      int gr = (r & 0x20) | (((r >> 2) & 3) << 3) | (((r >> 4) & 1) << 2) | (r & 3);
      const __bf16* ksrc = kbase + (size_t)(mt + gr) * HDIM + xr;
      __builtin_amdgcn_global_load_lds((guint*)ksrc,
                                       (suint*)&Kb[buf][wid * 16 + 8 * j][0],
                                       16, 0, 0);
      const __bf16* vsrc = vbase + (size_t)r * NN + mt + xr;
      __builtin_amdgcn_global_load_lds((guint*)vsrc,
                                       (suint*)&Vb[buf][wid * 16 + 8 * j][0],
                                       16, 0, 0);
    }
  };

  STAGE(0, 0);   // 4 loads in flight for buffer 0
  bf16x8 aq[2][2];
#pragma unroll
  for (int qg = 0; qg < 2; ++qg) {
    const __bf16* qp = qbase + (size_t)(wid * 32 + qg * 16 + c) * HDIM;
    aq[qg][0] = *(const bf16x8*)(qp + g * 8);
    aq[qg][1] = *(const bf16x8*)(qp + 32 + g * 8);
  }
  f32x4 O[2][4] = {};
  f32x4 Ol[2] = {};
  float m_[2] = {-1e30f, -1e30f};
  int cxor = (c & 7);
  const bf16x8 vones = {(__bf16)1.f, (__bf16)1.f, (__bf16)1.f, (__bf16)1.f,
                        (__bf16)1.f, (__bf16)1.f, (__bf16)1.f, (__bf16)1.f};

  for (int t = 0; t < KVQ / 64; ++t) {
    int cur = t & 1;
    if (t + 1 < KVQ / 64) {
      STAGE(cur ^ 1, (t + 1) * 64);
      asm volatile("s_waitcnt vmcnt(4)" ::: "memory");
    } else {
      asm volatile("s_waitcnt vmcnt(0)" ::: "memory");
    }
    __builtin_amdgcn_sched_barrier(0);
    __builtin_amdgcn_s_barrier();
    // ---- QK^T swapped ----
    f32x4 st[2][4];
    __builtin_amdgcn_s_setprio(1);
#pragma unroll
    for (int t4 = 0; t4 < 4; ++t4) {
      bf16x8 bk0 = *(const bf16x8*)&Kb[cur][t4 * 16 + c][(g ^ cxor) * 8];
      bf16x8 bk1 = *(const bf16x8*)&Kb[cur][t4 * 16 + c][((4 + g) ^ cxor) * 8];
#pragma unroll
      for (int qg = 0; qg < 2; ++qg) {
        f32x4 acc = {0.f, 0.f, 0.f, 0.f};
        acc = __builtin_amdgcn_mfma_f32_16x16x32_bf16(bk0, aq[qg][0], acc, 0, 0, 0);
        acc = __builtin_amdgcn_mfma_f32_16x16x32_bf16(bk1, aq[qg][1], acc, 0, 0, 0);
        st[qg][t4] = acc;
      }
    }
    __builtin_amdgcn_s_setprio(0);
    // ---- softmax ----
    bf16x8 pa[2][2];
#pragma unroll
    for (int qg = 0; qg < 2; ++qg) {
      float g0 = MX3(st[qg][0][0], st[qg][0][1], st[qg][0][2]);
      float g1 = MX3(st[qg][0][3], st[qg][1][0], st[qg][1][1]);
      float g2 = MX3(st[qg][1][2], st[qg][1][3], st[qg][2][0]);
      float g3 = MX3(st[qg][2][1], st[qg][2][2], st[qg][2][3]);
      float g4 = MX3(st[qg][3][0], st[qg][3][1], st[qg][3][2]);
      float pm = fmaxf(MX3(g0, g1, g2), MX3(g3, g4, st[qg][3][3]));
      if (!__all(pm <= m_[qg] + 8.0f)) {
        float rm = fmaxf(pm, __shfl_xor(pm, 16));
        rm = fmaxf(rm, __shfl_xor(rm, 32));
        float mn = fmaxf(m_[qg], rm);
        float fs = exp2f(m_[qg] - mn);
        m_[qg] = mn;
#pragma unroll
        for (int dt = 0; dt < 4; ++dt)
#pragma unroll
          for (int r = 0; r < 4; ++r) O[qg][dt][r] *= fs;
#pragma unroll
        for (int r = 0; r < 4; ++r) Ol[qg][r] *= fs;
      }
#pragma unroll
      for (int t4 = 0; t4 < 4; ++t4) {
        float p0 = exp2f(st[qg][t4][0] - m_[qg]);
        float p1 = exp2f(st[qg][t4][1] - m_[qg]);
        float p2 = exp2f(st[qg][t4][2] - m_[qg]);
        float p3 = exp2f(st[qg][t4][3] - m_[qg]);
        bf16x8* pp = &pa[qg][t4 >> 1];
        int o4 = (t4 & 1) * 4;
        (*pp)[o4 + 0] = (__bf16)p0;
        (*pp)[o4 + 1] = (__bf16)p1;
        (*pp)[o4 + 2] = (__bf16)p2;
        (*pp)[o4 + 3] = (__bf16)p3;
      }
    }
    // ---- PV swapped + ones-row l ----
    __builtin_amdgcn_s_setprio(1);
#pragma unroll
    for (int dt = 0; dt < 4; ++dt) {
      bf16x8 bv0 = *(const bf16x8*)&Vb[cur][dt * 16 + c][(g ^ cxor) * 8];
      bf16x8 bv1 = *(const bf16x8*)&Vb[cur][dt * 16 + c][((4 + g) ^ cxor) * 8];
#pragma unroll
      for (int qg = 0; qg < 2; ++qg) {
        O[qg][dt] = __builtin_amdgcn_mfma_f32_16x16x32_bf16(bv0, pa[qg][0],
                                                            O[qg][dt], 0, 0, 0);
        O[qg][dt] = __builtin_amdgcn_mfma_f32_16x16x32_bf16(bv1, pa[qg][1],
                                                            O[qg][dt], 0, 0, 0);
      }
    }
#pragma unroll
    for (int qg = 0; qg < 2; ++qg) {
      Ol[qg] = __builtin_amdgcn_mfma_f32_16x16x32_bf16(vones, pa[qg][0],
                                                       Ol[qg], 0, 0, 0);
      Ol[qg] = __builtin_amdgcn_mfma_f32_16x16x32_bf16(vones, pa[qg][1],
                                                       Ol[qg], 0, 0, 0);
    }
    __builtin_amdgcn_s_setprio(0);
    __builtin_amdgcn_s_barrier();
  }
  // ---- epilogue ----
#pragma unroll
  for (int qg = 0; qg < 2; ++qg) {
    size_t prow = ((size_t)(split * BB + b) * NHEADS + h) * NN +
                  (n0 + wid * 32 + qg * 16 + c);
#pragma unroll
    for (int dt = 0; dt < 4; ++dt) {
      bf16x4 pk = {(__bf16)O[qg][dt][0], (__bf16)O[qg][dt][1],
                   (__bf16)O[qg][dt][2], (__bf16)O[qg][dt][3]};
      *(bf16x4*)&opart[prow * HDIM + dt * 16 + 4 * g] = pk;
    }
    if (lane < 16) {
      float2 mlv = {m_[qg], Ol[qg][0]};
      *(float2*)&ml[prow * 2] = mlv;
    }
  }
}

// ---------------------------------------------------------------------------
// Kernel 3b: combine the four KV-split partials -> xa_t[b][n][c] bf16.
// ---------------------------------------------------------------------------
__global__ __launch_bounds__(256) void attn_combine_kernel(
    const __bf16* __restrict__ opart, const float* __restrict__ ml,
    __bf16* __restrict__ xa_t) {
  int t = threadIdx.x;
  int row_local = t >> 4;          // 0..15
  int dq = (t & 15) * 4;           // 0..60
  int R = blockIdx.x * 16 + row_local;  // global (b,h,n) row, 0..32767
  int n = R & (NN - 1);
  int bh = R >> 11;
  int b = bh >> 3, h = bh & 7;
  size_t ps[NSPLIT];
  float ms[NSPLIT], ls[NSPLIT];
  float m = -1e30f;
#pragma unroll
  for (int s = 0; s < NSPLIT; ++s) {
    ps[s] = ((size_t)(s * BB + b) * NHEADS + h) * NN + n;
    ms[s] = ml[ps[s] * 2];
    ls[s] = ml[ps[s] * 2 + 1];
    m = fmaxf(m, ms[s]);
  }
  float lsum = 0.f;
  float ws[NSPLIT];
#pragma unroll
  for (int s = 0; s < NSPLIT; ++s) {
    ws[s] = exp2f(ms[s] - m);
    lsum += ls[s] * ws[s];
  }
  float linv = 1.0f / lsum;
  float acc[4] = {0.f, 0.f, 0.f, 0.f};
#pragma unroll
  for (int s = 0; s < NSPLIT; ++s) {
    bf16x4 ov = *(const bf16x4*)&opart[ps[s] * HDIM + dq];
#pragma unroll
    for (int j = 0; j < 4; ++j) acc[j] += (float)ov[j] * ws[s];
  }
  bf16x4 pk = {(__bf16)(acc[0] * linv), (__bf16)(acc[1] * linv),
               (__bf16)(acc[2] * linv), (__bf16)(acc[3] * linv)};
  *(bf16x4*)&xa_t[((size_t)b * NN + n) * CC + h * HDIM + dq] = pk;
}

// ---------------------------------------------------------------------------
// Kernel 4: proj GEMM, reg-staged double-buffered LDS, 1 barrier per K-step,
// bias + residual(normalized x, fp32) epilogue.
// ---------------------------------------------------------------------------
__global__ __launch_bounds__(256) void proj_mfma_kernel(
    const __bf16* __restrict__ xa_t, const float* __restrict__ w,
    const float* __restrict__ bias, const float* __restrict__ x,
    const float* __restrict__ mu, const float* __restrict__ rstd,
    const float* __restrict__ lnw, const float* __restrict__ lnb,
    float* __restrict__ out) {
  __shared__ __align__(16) __bf16 As[2][64][68];
  __shared__ __align__(16) __bf16 Bs[2][64][68];
  int n0 = blockIdx.x * 64;
  int m0 = blockIdx.y * 64;
  int b = blockIdx.z;
  int tid = threadIdx.x;
  int wid = tid >> 6, lane = tid & 63;
  int g = lane >> 4, c = lane & 15;
  int wr = wid >> 1, wc = wid & 1;
  const __bf16* xab = xa_t + (size_t)b * NN * CC;
  int arow = tid >> 4, ac4 = tid & 15;
  int brow = tid >> 3, bc8 = tid & 7;

  float4 wA[4];
  bf16x8 xB[2];
  auto LOADREGS = [&](int k0) {
#pragma unroll
    for (int l = 0; l < 4; ++l)
      wA[l] = *(const float4*)&w[(size_t)(m0 + arow + 16 * l) * CC + k0 + ac4 * 4];
#pragma unroll
    for (int l = 0; l < 2; ++l)
      xB[l] = *(const bf16x8*)&xab[(size_t)(n0 + brow + 32 * l) * CC + k0 + bc8 * 8];
  };
  auto STORELDS = [&](int buf) {
#pragma unroll
    for (int l = 0; l < 4; ++l) {
      bf16x4 pk = {(__bf16)wA[l].x, (__bf16)wA[l].y, (__bf16)wA[l].z,
                   (__bf16)wA[l].w};
      *(bf16x4*)&As[buf][arow + 16 * l][ac4 * 4] = pk;
    }
#pragma unroll
    for (int l = 0; l < 2; ++l)
      *(bf16x8*)&Bs[buf][brow + 32 * l][bc8 * 8] = xB[l];
  };

  LOADREGS(0);
  STORELDS(0);
  __syncthreads();
  f32x4 acc[2][2] = {};
  for (int ktile = 0; ktile < 8; ++ktile) {
    int cur = ktile & 1;
    if (ktile < 7) LOADREGS((ktile + 1) * 64);
#pragma unroll
    for (int hh = 0; hh < 2; ++hh) {
      bf16x8 af[2], bfr[2];
#pragma unroll
      for (int mi = 0; mi < 2; ++mi)
        af[mi] = *(const bf16x8*)&As[cur][wr * 32 + mi * 16 + c][hh * 32 + g * 8];
#pragma unroll
      for (int nj = 0; nj < 2; ++nj)
        bfr[nj] = *(const bf16x8*)&Bs[cur][wc * 32 + nj * 16 + c][hh * 32 + g * 8];
#pragma unroll
      for (int mi = 0; mi < 2; ++mi)
#pragma unroll
        for (int nj = 0; nj < 2; ++nj)
          acc[mi][nj] = __builtin_amdgcn_mfma_f32_16x16x32_bf16(
              af[mi], bfr[nj], acc[mi][nj], 0, 0, 0);
    }
    if (ktile < 7) STORELDS(cur ^ 1);
    __syncthreads();
  }
#pragma unroll
  for (int mi = 0; mi < 2; ++mi)
#pragma unroll
    for (int r = 0; r < 4; ++r) {
      int o = m0 + wr * 32 + mi * 16 + 4 * g + r;
      float bo = bias[o], gw = lnw[o], gb = lnb[o];
#pragma unroll
      for (int nj = 0; nj < 2; ++nj) {
        int n = n0 + wc * 32 + nj * 16 + c;
        int tok = b * NN + n;
        float xv = x[((size_t)b * CC + o) * NN + n];
        float xlnv = (xv - mu[tok]) * rstd[tok] * gw + gb;
        out[((size_t)b * CC + o) * NN + n] = acc[mi][nj][r] + bo + xlnv;
      }
    }
}

// ---------------------------------------------------------------------------
extern "C" void kernel_launch(void* const* d_in, const int* in_sizes, int n_in,
                              void* d_out, int out_size, void* d_ws, size_t ws_size,
                              hipStream_t stream) {
  const float* x = (const float*)d_in[0];
  const float* lnw = (const float*)d_in[1];
  const float* lnb = (const float*)d_in[2];
  const float* wqkv = (const float*)d_in[3];
  const float* bqkv = (const float*)d_in[4];
  const float* wproj = (const float*)d_in[5];
  const float* bproj = (const float*)d_in[6];
  float* out = (float*)d_out;
  (void)in_sizes; (void)n_in; (void)out_size; (void)ws_size;

  char* wsb = (char*)d_ws;
  float* mu = (float*)wsb;                               // 16 KB
  float* rstd = mu + 4096;                               // 16 KB
  const size_t HSZ = (size_t)BB * NHEADS * NN * HDIM;    // 2M elems
  __bf16* qt = (__bf16*)(wsb + 32768);                   // 4 MB
  __bf16* kt = qt + HSZ;                                 // 4 MB
  __bf16* vbf = kt + HSZ;                                // 4 MB
  __bf16* xa_t = vbf + HSZ;                              // 4 MB
  __bf16* xln_t = xa_t + HSZ;                            // 4 MB (dead after qkv)
  // opart overlays xln_t's region and extends: 4 splits x 4 MB bf16 = 16 MB
  __bf16* opart = xln_t;
  float* ml = (float*)(wsb + 32768 + 4 * HSZ * sizeof(__bf16) +
                       (size_t)NSPLIT * HSZ * sizeof(__bf16));  // 1 MB

  hipLaunchKernelGGL(ln_fused_kernel, dim3(128, 2), dim3(256), 0, stream,
                     x, lnw, lnb, mu, rstd, xln_t);
  hipLaunchKernelGGL(qkv_mfma_kernel, dim3(16, 24, 2), dim3(256), 0, stream,
                     xln_t, wqkv, bqkv, qt, kt, vbf);
  hipLaunchKernelGGL(attn_mfma_kernel, dim3(16, 8, BB * NSPLIT), dim3(256), 0,
                     stream, qt, kt, vbf, opart, ml);
  hipLaunchKernelGGL(attn_combine_kernel, dim3(2048), dim3(256), 0, stream,
                     opart, ml, xa_t);
  hipLaunchKernelGGL(proj_mfma_kernel, dim3(32, 8, 2), dim3(256), 0, stream,
                     xa_t, wproj, bproj, x, mu, rstd, lnw, lnb, out);
}

// Round 15
// 76.144 us; speedup vs baseline: 1.2289x; 1.0182x over previous
//
#include <hip/hip_runtime.h>
#include <hip/hip_bf16.h>

// Problem constants
#define BB 2
#define CC 512
#define NN 2048          // T*H*W = 8*16*16
#define NHEADS 8
#define HDIM 64
#define NSPLIT 2
#define KVQ 1024         // NN / NSPLIT

typedef __attribute__((ext_vector_type(8))) __bf16 bf16x8;
typedef __attribute__((ext_vector_type(4))) __bf16 bf16x4;
typedef __attribute__((ext_vector_type(4))) float f32x4;

typedef const __attribute__((address_space(1))) unsigned int guint;
typedef __attribute__((address_space(3))) unsigned int suint;

#define QSCALE 0.18033688f  // 0.125 * log2(e): QK^T lands in exp2 domain
#define MX3(a, b, c) fmaxf(fmaxf(a, b), c)

// ---------------------------------------------------------------------------
// Kernel 0: one-shot fp32 -> bf16 weight conversion (wqkv 1536x512, wproj
// 512x512). Removes per-K-step cvt + fp32 fetch from both GEMMs.
// ---------------------------------------------------------------------------
__global__ __launch_bounds__(256) void cvt_w_kernel(
    const float* __restrict__ wqkv, const float* __restrict__ wproj,
    __bf16* __restrict__ wqkv_bf, __bf16* __restrict__ wproj_bf) {
  int i = blockIdx.x * 256 + threadIdx.x;  // 0..262143, 4 elems each
  const int NQ = 3 * CC * CC / 4;          // 196608
  if (i < NQ) {
    float4 v = *(const float4*)&wqkv[(size_t)i * 4];
    bf16x4 pk = {(__bf16)v.x, (__bf16)v.y, (__bf16)v.z, (__bf16)v.w};
    *(bf16x4*)&wqkv_bf[(size_t)i * 4] = pk;
  } else {
    int j = i - NQ;                        // 0..65535
    float4 v = *(const float4*)&wproj[(size_t)j * 4];
    bf16x4 pk = {(__bf16)v.x, (__bf16)v.y, (__bf16)v.z, (__bf16)v.w};
    *(bf16x4*)&wproj_bf[(size_t)j * 4] = pk;
  }
}

// ---------------------------------------------------------------------------
// Kernel 1 (FUSED): LayerNorm stats + apply + transpose in ONE pass over x.
// ---------------------------------------------------------------------------
__global__ __launch_bounds__(256) void ln_fused_kernel(
    const float* __restrict__ x, const float* __restrict__ lnw,
    const float* __restrict__ lnb, float* __restrict__ mu,
    float* __restrict__ rstd, __bf16* __restrict__ xln_t) {
  __shared__ float Xs[512][20];   // 40 KiB; stride 20 floats = 80B
  __shared__ float rs[16][17];
  __shared__ float rq[16][17];
  __shared__ float mloc[16];
  __shared__ float rloc[16];
  int bid = blockIdx.x;           // [0,128)
  int n_tile = 2 * (((bid >> 4) << 3) + (bid & 7)) + ((bid >> 3) & 1);
  int n0 = n_tile * 16;
  int b = blockIdx.y;
  int tid = threadIdx.x;
#pragma unroll
  for (int l = 0; l < 8; ++l) {
    int e = tid + 256 * l;
    int row = e >> 2, quad = e & 3;
    float4 v = *(const float4*)&x[((size_t)b * CC + row) * NN + n0 + quad * 4];
    *(float4*)&Xs[row][quad * 4] = v;
  }
  __syncthreads();
  {
    int tk = tid & 15, part = tid >> 4;
    float s = 0.f, ss = 0.f;
    int c0 = part * 32;
#pragma unroll 8
    for (int j = 0; j < 32; ++j) {
      float v = Xs[c0 + j][tk];
      s += v;
      ss += v * v;
    }
    rs[part][tk] = s;
    rq[part][tk] = ss;
  }
  __syncthreads();
  if (tid < 16) {
    float S = 0.f, SS = 0.f;
#pragma unroll
    for (int p = 0; p < 16; ++p) {
      S += rs[p][tid];
      SS += rq[p][tid];
    }
    float m = S * (1.0f / CC);
    float var = SS * (1.0f / CC) - m * m;
    float rv = rsqrtf(var + 1e-5f);
    mloc[tid] = m;
    rloc[tid] = rv;
    int tok = b * NN + n0 + tid;
    mu[tok] = m;
    rstd[tok] = rv;
  }
  __syncthreads();
  {
    int tk = tid >> 4;
    int cseg = (tid & 15) * 32;
    float mun = mloc[tk], rsn = rloc[tk];
    __bf16 outv[32];
#pragma unroll
    for (int j = 0; j < 32; ++j) {
      int c = cseg + j;
      outv[j] = (__bf16)((Xs[c][tk] - mun) * rsn * lnw[c] + lnb[c]);
    }
    __bf16* dst = &xln_t[((size_t)b * NN + n0 + tk) * CC + cseg];
#pragma unroll
    for (int q = 0; q < 4; ++q) *(bf16x8*)&dst[q * 8] = *(bf16x8*)&outv[q * 8];
  }
}

// ---------------------------------------------------------------------------
// Kernel 2: merged QKV GEMM, bf16 MFMA, global_load_lds staging with XOR
// chunk swizzle (attn-verified pattern, 0 bank conflicts), counted-vmcnt
// double buffer. blockIdx.y<16 -> q/k (swapped mfma, [n][d] out); else v.
// ---------------------------------------------------------------------------
__global__ __launch_bounds__(256, 3) void qkv_mfma_kernel(
    const __bf16* __restrict__ xln_t, const __bf16* __restrict__ wbf,
    const float* __restrict__ bias, __bf16* __restrict__ qt,
    __bf16* __restrict__ kt, __bf16* __restrict__ vbf) {
  __shared__ __align__(16) __bf16 As[2][64][64];   // 8 KiB each
  __shared__ __align__(16) __bf16 Bs[2][128][64];  // 16 KiB each
  int n0 = blockIdx.x * 128;
  bool swap = blockIdx.y < 16;
  int m0 = swap ? blockIdx.y * 64 : 1024 + ((int)blockIdx.y - 16) * 64;
  int b = blockIdx.z;
  int tid = threadIdx.x;
  int wid = tid >> 6, lane = tid & 63;
  int g = lane >> 4, c = lane & 15;
  int wr = wid >> 1, wc = wid & 1;
  const __bf16* xln = xln_t + (size_t)b * NN * CC;
  int l7 = lane & 7, l3 = lane >> 3;
  int xr = (l7 ^ l3) * 8;            // XOR-swizzled source chunk
  auto STAGE = [&](int buf, int k0) {
#pragma unroll
    for (int j = 0; j < 2; ++j) {
      int r = wid * 16 + 8 * j + l3;
      __builtin_amdgcn_global_load_lds(
          (guint*)(wbf + (size_t)(m0 + r) * CC + k0 + xr),
          (suint*)&As[buf][wid * 16 + 8 * j][0], 16, 0, 0);
    }
#pragma unroll
    for (int j = 0; j < 4; ++j) {
      int r = wid * 32 + 8 * j + l3;
      __builtin_amdgcn_global_load_lds(
          (guint*)(xln + (size_t)(n0 + r) * CC + k0 + xr),
          (suint*)&Bs[buf][wid * 32 + 8 * j][0], 16, 0, 0);
    }
  };
  STAGE(0, 0);   // 6 loads in flight
  f32x4 acc[2][4] = {};
  int cxor = c & 7;
  for (int ks = 0; ks < 8; ++ks) {
    int cur = ks & 1;
    if (ks < 7) {
      STAGE(cur ^ 1, (ks + 1) * 64);
      asm volatile("s_waitcnt vmcnt(6)" ::: "memory");
    } else {
      asm volatile("s_waitcnt vmcnt(0)" ::: "memory");
    }
    __builtin_amdgcn_sched_barrier(0);
    __builtin_amdgcn_s_barrier();
    __builtin_amdgcn_s_setprio(1);
#pragma unroll
    for (int hh = 0; hh < 2; ++hh) {
      int ch = ((hh * 4 + g) ^ cxor) * 8;
      bf16x8 af[2], bfr[4];
#pragma unroll
      for (int mi = 0; mi < 2; ++mi)
        af[mi] = *(const bf16x8*)&As[cur][wr * 32 + mi * 16 + c][ch];
#pragma unroll
      for (int nj = 0; nj < 4; ++nj)
        bfr[nj] = *(const bf16x8*)&Bs[cur][wc * 64 + nj * 16 + c][ch];
      if (swap) {
#pragma unroll
        for (int mi = 0; mi < 2; ++mi)
#pragma unroll
          for (int nj = 0; nj < 4; ++nj)
            acc[mi][nj] = __builtin_amdgcn_mfma_f32_16x16x32_bf16(
                bfr[nj], af[mi], acc[mi][nj], 0, 0, 0);
      } else {
#pragma unroll
        for (int mi = 0; mi < 2; ++mi)
#pragma unroll
          for (int nj = 0; nj < 4; ++nj)
            acc[mi][nj] = __builtin_amdgcn_mfma_f32_16x16x32_bf16(
                af[mi], bfr[nj], acc[mi][nj], 0, 0, 0);
      }
    }
    __builtin_amdgcn_s_setprio(0);
    __builtin_amdgcn_s_barrier();  // all reads done before next STAGE lands
  }
  if (swap) {
    int obase = m0 + wr * 32;
    int sec = obase >> 9;  // 0=q, 1=k
    int osec = obase & 511;
    int head = osec >> 6;
    int dbase = osec & 63;
    __bf16* dst = (sec == 0 ? qt : kt) + (size_t)(b * NHEADS + head) * NN * HDIM;
    float scl = (sec == 0) ? QSCALE : 1.0f;
#pragma unroll
    for (int mi = 0; mi < 2; ++mi) {
      float bo = bias[obase + mi * 16 + c];
      int d = dbase + mi * 16 + c;
#pragma unroll
      for (int nj = 0; nj < 4; ++nj)
#pragma unroll
        for (int r = 0; r < 4; ++r) {
          int n = n0 + wc * 64 + nj * 16 + 4 * g + r;
          dst[(size_t)n * HDIM + d] = (__bf16)((acc[mi][nj][r] + bo) * scl);
        }
    }
  } else {
#pragma unroll
    for (int mi = 0; mi < 2; ++mi)
#pragma unroll
      for (int r = 0; r < 4; ++r) {
        int o = m0 + wr * 32 + mi * 16 + 4 * g + r;
        int ch = o - 1024;
        float bo = bias[o];
#pragma unroll
        for (int nj = 0; nj < 4; ++nj) {
          int n = n0 + wc * 64 + nj * 16 + c;
          vbf[((size_t)b * CC + ch) * NN + n] = (__bf16)(acc[mi][nj][r] + bo);
        }
      }
  }
}

// ---------------------------------------------------------------------------
// Kernel 3: flash attention, split-KV x2, 4 waves x 256 thr, QBLK=128,
// 2 q-groups per wave, lane-local defer softmax, ones-MFMA l, max3 tree,
// counted-vmcnt double buffer (R13 structure).
// ---------------------------------------------------------------------------
__global__ __launch_bounds__(256, 3) void attn_mfma_kernel(
    const __bf16* __restrict__ qt, const __bf16* __restrict__ ktg,
    const __bf16* __restrict__ vbf, __bf16* __restrict__ opart,
    float* __restrict__ ml) {
  __shared__ __align__(16) __bf16 Kb[2][64][64];  // 16 KiB
  __shared__ __align__(16) __bf16 Vb[2][64][64];  // 16 KiB
  int tid = threadIdx.x;
  int wid = tid >> 6, lane = tid & 63;
  int g = lane >> 4, c = lane & 15;
  int n0 = blockIdx.x * 128;
  int h = blockIdx.y;
  int b = blockIdx.z >> 1, split = blockIdx.z & 1;
  int bh = b * NHEADS + h;
  const __bf16* qbase = qt + ((size_t)bh * NN + n0) * HDIM;
  const __bf16* kbase = ktg + ((size_t)bh * NN + split * KVQ) * HDIM;
  const __bf16* vbase = vbf + ((size_t)b * CC + h * HDIM) * NN + split * KVQ;

  int l7 = lane & 7, l3 = lane >> 3;
  int xr = (l7 ^ l3) * 8;
  auto STAGE = [&](int buf, int mt) {
#pragma unroll
    for (int j = 0; j < 2; ++j) {
      int r = wid * 16 + 8 * j + l3;
      int gr = (r & 0x20) | (((r >> 2) & 3) << 3) | (((r >> 4) & 1) << 2) | (r & 3);
      const __bf16* ksrc = kbase + (size_t)(mt + gr) * HDIM + xr;
      __builtin_amdgcn_global_load_lds((guint*)ksrc,
                                       (suint*)&Kb[buf][wid * 16 + 8 * j][0],
                                       16, 0, 0);
      const __bf16* vsrc = vbase + (size_t)r * NN + mt + xr;
      __builtin_amdgcn_global_load_lds((guint*)vsrc,
                                       (suint*)&Vb[buf][wid * 16 + 8 * j][0],
                                       16, 0, 0);
    }
  };

  STAGE(0, 0);
  bf16x8 aq[2][2];
#pragma unroll
  for (int qg = 0; qg < 2; ++qg) {
    const __bf16* qp = qbase + (size_t)(wid * 32 + qg * 16 + c) * HDIM;
    aq[qg][0] = *(const bf16x8*)(qp + g * 8);
    aq[qg][1] = *(const bf16x8*)(qp + 32 + g * 8);
  }
  f32x4 O[2][4] = {};
  f32x4 Ol[2] = {};
  float m_[2] = {-1e30f, -1e30f};
  int cxor = (c & 7);
  const bf16x8 vones = {(__bf16)1.f, (__bf16)1.f, (__bf16)1.f, (__bf16)1.f,
                        (__bf16)1.f, (__bf16)1.f, (__bf16)1.f, (__bf16)1.f};

  for (int t = 0; t < KVQ / 64; ++t) {
    int cur = t & 1;
    if (t + 1 < KVQ / 64) {
      STAGE(cur ^ 1, (t + 1) * 64);
      asm volatile("s_waitcnt vmcnt(4)" ::: "memory");
    } else {
      asm volatile("s_waitcnt vmcnt(0)" ::: "memory");
    }
    __builtin_amdgcn_sched_barrier(0);
    __builtin_amdgcn_s_barrier();
    f32x4 st[2][4];
    __builtin_amdgcn_s_setprio(1);
#pragma unroll
    for (int t4 = 0; t4 < 4; ++t4) {
      bf16x8 bk0 = *(const bf16x8*)&Kb[cur][t4 * 16 + c][(g ^ cxor) * 8];
      bf16x8 bk1 = *(const bf16x8*)&Kb[cur][t4 * 16 + c][((4 + g) ^ cxor) * 8];
#pragma unroll
      for (int qg = 0; qg < 2; ++qg) {
        f32x4 acc = {0.f, 0.f, 0.f, 0.f};
        acc = __builtin_amdgcn_mfma_f32_16x16x32_bf16(bk0, aq[qg][0], acc, 0, 0, 0);
        acc = __builtin_amdgcn_mfma_f32_16x16x32_bf16(bk1, aq[qg][1], acc, 0, 0, 0);
        st[qg][t4] = acc;
      }
    }
    __builtin_amdgcn_s_setprio(0);
    bf16x8 pa[2][2];
#pragma unroll
    for (int qg = 0; qg < 2; ++qg) {
      float g0 = MX3(st[qg][0][0], st[qg][0][1], st[qg][0][2]);
      float g1 = MX3(st[qg][0][3], st[qg][1][0], st[qg][1][1]);
      float g2 = MX3(st[qg][1][2], st[qg][1][3], st[qg][2][0]);
      float g3 = MX3(st[qg][2][1], st[qg][2][2], st[qg][2][3]);
      float g4 = MX3(st[qg][3][0], st[qg][3][1], st[qg][3][2]);
      float pm = fmaxf(MX3(g0, g1, g2), MX3(g3, g4, st[qg][3][3]));
      if (!__all(pm <= m_[qg] + 8.0f)) {
        float rm = fmaxf(pm, __shfl_xor(pm, 16));
        rm = fmaxf(rm, __shfl_xor(rm, 32));
        float mn = fmaxf(m_[qg], rm);
        float fs = exp2f(m_[qg] - mn);
        m_[qg] = mn;
#pragma unroll
        for (int dt = 0; dt < 4; ++dt)
#pragma unroll
          for (int r = 0; r < 4; ++r) O[qg][dt][r] *= fs;
#pragma unroll
        for (int r = 0; r < 4; ++r) Ol[qg][r] *= fs;
      }
#pragma unroll
      for (int t4 = 0; t4 < 4; ++t4) {
        float p0 = exp2f(st[qg][t4][0] - m_[qg]);
        float p1 = exp2f(st[qg][t4][1] - m_[qg]);
        float p2 = exp2f(st[qg][t4][2] - m_[qg]);
        float p3 = exp2f(st[qg][t4][3] - m_[qg]);
        bf16x8* pp = &pa[qg][t4 >> 1];
        int o4 = (t4 & 1) * 4;
        (*pp)[o4 + 0] = (__bf16)p0;
        (*pp)[o4 + 1] = (__bf16)p1;
        (*pp)[o4 + 2] = (__bf16)p2;
        (*pp)[o4 + 3] = (__bf16)p3;
      }
    }
    __builtin_amdgcn_s_setprio(1);
#pragma unroll
    for (int dt = 0; dt < 4; ++dt) {
      bf16x8 bv0 = *(const bf16x8*)&Vb[cur][dt * 16 + c][(g ^ cxor) * 8];
      bf16x8 bv1 = *(const bf16x8*)&Vb[cur][dt * 16 + c][((4 + g) ^ cxor) * 8];
#pragma unroll
      for (int qg = 0; qg < 2; ++qg) {
        O[qg][dt] = __builtin_amdgcn_mfma_f32_16x16x32_bf16(bv0, pa[qg][0],
                                                            O[qg][dt], 0, 0, 0);
        O[qg][dt] = __builtin_amdgcn_mfma_f32_16x16x32_bf16(bv1, pa[qg][1],
                                                            O[qg][dt], 0, 0, 0);
      }
    }
#pragma unroll
    for (int qg = 0; qg < 2; ++qg) {
      Ol[qg] = __builtin_amdgcn_mfma_f32_16x16x32_bf16(vones, pa[qg][0],
                                                       Ol[qg], 0, 0, 0);
      Ol[qg] = __builtin_amdgcn_mfma_f32_16x16x32_bf16(vones, pa[qg][1],
                                                       Ol[qg], 0, 0, 0);
    }
    __builtin_amdgcn_s_setprio(0);
    __builtin_amdgcn_s_barrier();
  }
#pragma unroll
  for (int qg = 0; qg < 2; ++qg) {
    size_t prow = ((size_t)(split * BB + b) * NHEADS + h) * NN +
                  (n0 + wid * 32 + qg * 16 + c);
#pragma unroll
    for (int dt = 0; dt < 4; ++dt) {
      bf16x4 pk = {(__bf16)O[qg][dt][0], (__bf16)O[qg][dt][1],
                   (__bf16)O[qg][dt][2], (__bf16)O[qg][dt][3]};
      *(bf16x4*)&opart[prow * HDIM + dt * 16 + 4 * g] = pk;
    }
    if (lane < 16) {
      float2 mlv = {m_[qg], Ol[qg][0]};
      *(float2*)&ml[prow * 2] = mlv;
    }
  }
}

// ---------------------------------------------------------------------------
// Kernel 3b: combine the two KV-split partials -> xa_t[b][n][c] bf16.
// ---------------------------------------------------------------------------
__global__ __launch_bounds__(256) void attn_combine_kernel(
    const __bf16* __restrict__ opart, const float* __restrict__ ml,
    __bf16* __restrict__ xa_t) {
  int t = threadIdx.x;
  int row_local = t >> 4;
  int dq = (t & 15) * 4;
  int R = blockIdx.x * 16 + row_local;
  int n = R & (NN - 1);
  int bh = R >> 11;
  int b = bh >> 3, h = bh & 7;
  size_t ps[NSPLIT];
  float ms[NSPLIT], ls[NSPLIT];
  float m = -1e30f;
#pragma unroll
  for (int s = 0; s < NSPLIT; ++s) {
    ps[s] = ((size_t)(s * BB + b) * NHEADS + h) * NN + n;
    ms[s] = ml[ps[s] * 2];
    ls[s] = ml[ps[s] * 2 + 1];
    m = fmaxf(m, ms[s]);
  }
  float lsum = 0.f;
  float ws[NSPLIT];
#pragma unroll
  for (int s = 0; s < NSPLIT; ++s) {
    ws[s] = exp2f(ms[s] - m);
    lsum += ls[s] * ws[s];
  }
  float linv = 1.0f / lsum;
  float acc[4] = {0.f, 0.f, 0.f, 0.f};
#pragma unroll
  for (int s = 0; s < NSPLIT; ++s) {
    bf16x4 ov = *(const bf16x4*)&opart[ps[s] * HDIM + dq];
#pragma unroll
    for (int j = 0; j < 4; ++j) acc[j] += (float)ov[j] * ws[s];
  }
  bf16x4 pk = {(__bf16)(acc[0] * linv), (__bf16)(acc[1] * linv),
               (__bf16)(acc[2] * linv), (__bf16)(acc[3] * linv)};
  *(bf16x4*)&xa_t[((size_t)b * NN + n) * CC + h * HDIM + dq] = pk;
}

// ---------------------------------------------------------------------------
// Kernel 4: proj GEMM, global_load_lds staging + counted vmcnt (same recipe),
// bias + residual(normalized x, fp32) epilogue.
// ---------------------------------------------------------------------------
__global__ __launch_bounds__(256, 4) void proj_mfma_kernel(
    const __bf16* __restrict__ xa_t, const __bf16* __restrict__ wbf,
    const float* __restrict__ bias, const float* __restrict__ x,
    const float* __restrict__ mu, const float* __restrict__ rstd,
    const float* __restrict__ lnw, const float* __restrict__ lnb,
    float* __restrict__ out) {
  __shared__ __align__(16) __bf16 As[2][64][64];  // 8 KiB each
  __shared__ __align__(16) __bf16 Bs[2][64][64];  // 8 KiB each
  int n0 = blockIdx.x * 64;
  int m0 = blockIdx.y * 64;
  int b = blockIdx.z;
  int tid = threadIdx.x;
  int wid = tid >> 6, lane = tid & 63;
  int g = lane >> 4, c = lane & 15;
  int wr = wid >> 1, wc = wid & 1;
  const __bf16* xab = xa_t + (size_t)b * NN * CC;
  int l7 = lane & 7, l3 = lane >> 3;
  int xr = (l7 ^ l3) * 8;
  auto STAGE = [&](int buf, int k0) {
#pragma unroll
    for (int j = 0; j < 2; ++j) {
      int r = wid * 16 + 8 * j + l3;
      __builtin_amdgcn_global_load_lds(
          (guint*)(wbf + (size_t)(m0 + r) * CC + k0 + xr),
          (suint*)&As[buf][wid * 16 + 8 * j][0], 16, 0, 0);
      __builtin_amdgcn_global_load_lds(
          (guint*)(xab + (size_t)(n0 + r) * CC + k0 + xr),
          (suint*)&Bs[buf][wid * 16 + 8 * j][0], 16, 0, 0);
    }
  };
  STAGE(0, 0);
  f32x4 acc[2][2] = {};
  int cxor = c & 7;
  for (int ks = 0; ks < 8; ++ks) {
    int cur = ks & 1;
    if (ks < 7) {
      STAGE(cur ^ 1, (ks + 1) * 64);
      asm volatile("s_waitcnt vmcnt(4)" ::: "memory");
    } else {
      asm volatile("s_waitcnt vmcnt(0)" ::: "memory");
    }
    __builtin_amdgcn_sched_barrier(0);
    __builtin_amdgcn_s_barrier();
    __builtin_amdgcn_s_setprio(1);
#pragma unroll
    for (int hh = 0; hh < 2; ++hh) {
      int ch = ((hh * 4 + g) ^ cxor) * 8;
      bf16x8 af[2], bfr[2];
#pragma unroll
      for (int mi = 0; mi < 2; ++mi)
        af[mi] = *(const bf16x8*)&As[cur][wr * 32 + mi * 16 + c][ch];
#pragma unroll
      for (int nj = 0; nj < 2; ++nj)
        bfr[nj] = *(const bf16x8*)&Bs[cur][wc * 32 + nj * 16 + c][ch];
#pragma unroll
      for (int mi = 0; mi < 2; ++mi)
#pragma unroll
        for (int nj = 0; nj < 2; ++nj)
          acc[mi][nj] = __builtin_amdgcn_mfma_f32_16x16x32_bf16(
              af[mi], bfr[nj], acc[mi][nj], 0, 0, 0);
    }
    __builtin_amdgcn_s_setprio(0);
    __builtin_amdgcn_s_barrier();
  }
#pragma unroll
  for (int mi = 0; mi < 2; ++mi)
#pragma unroll
    for (int r = 0; r < 4; ++r) {
      int o = m0 + wr * 32 + mi * 16 + 4 * g + r;
      float bo = bias[o], gw = lnw[o], gb = lnb[o];
#pragma unroll
      for (int nj = 0; nj < 2; ++nj) {
        int n = n0 + wc * 32 + nj * 16 + c;
        int tok = b * NN + n;
        float xv = x[((size_t)b * CC + o) * NN + n];
        float xlnv = (xv - mu[tok]) * rstd[tok] * gw + gb;
        out[((size_t)b * CC + o) * NN + n] = acc[mi][nj][r] + bo + xlnv;
      }
    }
}

// ---------------------------------------------------------------------------
extern "C" void kernel_launch(void* const* d_in, const int* in_sizes, int n_in,
                              void* d_out, int out_size, void* d_ws, size_t ws_size,
                              hipStream_t stream) {
  const float* x = (const float*)d_in[0];
  const float* lnw = (const float*)d_in[1];
  const float* lnb = (const float*)d_in[2];
  const float* wqkv = (const float*)d_in[3];
  const float* bqkv = (const float*)d_in[4];
  const float* wproj = (const float*)d_in[5];
  const float* bproj = (const float*)d_in[6];
  float* out = (float*)d_out;
  (void)in_sizes; (void)n_in; (void)out_size; (void)ws_size;

  char* wsb = (char*)d_ws;
  float* mu = (float*)wsb;                               // 16 KB
  float* rstd = mu + 4096;                               // 16 KB
  const size_t HSZ = (size_t)BB * NHEADS * NN * HDIM;    // 2M elems
  __bf16* qt = (__bf16*)(wsb + 32768);                   // 4 MB
  __bf16* kt = qt + HSZ;                                 // 4 MB
  __bf16* vbf = kt + HSZ;                                // 4 MB
  __bf16* xa_t = vbf + HSZ;                              // 4 MB
  __bf16* xln_t = xa_t + HSZ;                            // 4 MB (kept live)
  __bf16* opart = xln_t + HSZ;                           // 2 x 4 MB = 8 MB
  float* ml = (float*)(opart + (size_t)NSPLIT * HSZ);    // 512 KB
  __bf16* wqkv_bf = (__bf16*)((char*)ml + 524288);       // 1.5 MB
  __bf16* wproj_bf = wqkv_bf + (size_t)3 * CC * CC;      // 0.5 MB
  // total ~30.6 MB

  hipLaunchKernelGGL(cvt_w_kernel, dim3(1024), dim3(256), 0, stream,
                     wqkv, wproj, wqkv_bf, wproj_bf);
  hipLaunchKernelGGL(ln_fused_kernel, dim3(128, 2), dim3(256), 0, stream,
                     x, lnw, lnb, mu, rstd, xln_t);
  hipLaunchKernelGGL(qkv_mfma_kernel, dim3(16, 24, 2), dim3(256), 0, stream,
                     xln_t, wqkv_bf, bqkv, qt, kt, vbf);
  hipLaunchKernelGGL(attn_mfma_kernel, dim3(16, 8, BB * NSPLIT), dim3(256), 0,
                     stream, qt, kt, vbf, opart, ml);
  hipLaunchKernelGGL(attn_combine_kernel, dim3(2048), dim3(256), 0, stream,
                     opart, ml, xa_t);
  hipLaunchKernelGGL(proj_mfma_kernel, dim3(32, 8, 2), dim3(256), 0, stream,
                     xa_t, wproj_bf, bproj, x, mu, rstd, lnw, lnb, out);
}

// Round 16
// 71.517 us; speedup vs baseline: 1.3084x; 1.0647x over previous
//
#include <hip/hip_runtime.h>
#include <hip/hip_bf16.h>

// Problem constants
#define BB 2
#define CC 512
#define NN 2048          // T*H*W = 8*16*16
#define NHEADS 8
#define HDIM 64
#define NSPLIT 2
#define KVQ 1024         // NN / NSPLIT

typedef __attribute__((ext_vector_type(8))) __bf16 bf16x8;
typedef __attribute__((ext_vector_type(4))) __bf16 bf16x4;
typedef __attribute__((ext_vector_type(4))) float f32x4;

typedef const __attribute__((address_space(1))) unsigned int guint;
typedef __attribute__((address_space(3))) unsigned int suint;

#define QSCALE 0.18033688f  // 0.125 * log2(e): QK^T lands in exp2 domain
#define MX3(a, b, c) fmaxf(fmaxf(a, b), c)

// ---------------------------------------------------------------------------
// Kernel 1 (MERGED): blocks [0,256): LayerNorm stats+apply+transpose;
// blocks [256,1280): fp32->bf16 weight conversion. One launch fewer.
// ---------------------------------------------------------------------------
__global__ __launch_bounds__(256) void ln_cvt_kernel(
    const float* __restrict__ x, const float* __restrict__ lnw,
    const float* __restrict__ lnb, const float* __restrict__ wqkv,
    const float* __restrict__ wproj, float* __restrict__ mu,
    float* __restrict__ rstd, __bf16* __restrict__ xln_t,
    __bf16* __restrict__ wqkv_bf, __bf16* __restrict__ wproj_bf) {
  __shared__ float Xs[512][20];   // 40 KiB
  __shared__ float rs[16][17];
  __shared__ float rq[16][17];
  __shared__ float mloc[16];
  __shared__ float rloc[16];
  int tid = threadIdx.x;
  if (blockIdx.x >= 256) {  // ---- weight cvt part ----
    int i = (blockIdx.x - 256) * 256 + tid;  // 4 elems each
    const int NQ = 3 * CC * CC / 4;          // 196608
    if (i < NQ) {
      float4 v = *(const float4*)&wqkv[(size_t)i * 4];
      bf16x4 pk = {(__bf16)v.x, (__bf16)v.y, (__bf16)v.z, (__bf16)v.w};
      *(bf16x4*)&wqkv_bf[(size_t)i * 4] = pk;
    } else {
      int j = i - NQ;
      float4 v = *(const float4*)&wproj[(size_t)j * 4];
      bf16x4 pk = {(__bf16)v.x, (__bf16)v.y, (__bf16)v.z, (__bf16)v.w};
      *(bf16x4*)&wproj_bf[(size_t)j * 4] = pk;
    }
    return;
  }
  int bid = blockIdx.x & 127;
  int b = blockIdx.x >> 7;
  int n_tile = 2 * (((bid >> 4) << 3) + (bid & 7)) + ((bid >> 3) & 1);
  int n0 = n_tile * 16;
#pragma unroll
  for (int l = 0; l < 8; ++l) {
    int e = tid + 256 * l;
    int row = e >> 2, quad = e & 3;
    float4 v = *(const float4*)&x[((size_t)b * CC + row) * NN + n0 + quad * 4];
    *(float4*)&Xs[row][quad * 4] = v;
  }
  __syncthreads();
  {
    int tk = tid & 15, part = tid >> 4;
    float s = 0.f, ss = 0.f;
    int c0 = part * 32;
#pragma unroll 8
    for (int j = 0; j < 32; ++j) {
      float v = Xs[c0 + j][tk];
      s += v;
      ss += v * v;
    }
    rs[part][tk] = s;
    rq[part][tk] = ss;
  }
  __syncthreads();
  if (tid < 16) {
    float S = 0.f, SS = 0.f;
#pragma unroll
    for (int p = 0; p < 16; ++p) {
      S += rs[p][tid];
      SS += rq[p][tid];
    }
    float m = S * (1.0f / CC);
    float var = SS * (1.0f / CC) - m * m;
    float rv = rsqrtf(var + 1e-5f);
    mloc[tid] = m;
    rloc[tid] = rv;
    int tok = b * NN + n0 + tid;
    mu[tok] = m;
    rstd[tok] = rv;
  }
  __syncthreads();
  {
    int tk = tid >> 4;
    int cseg = (tid & 15) * 32;
    float mun = mloc[tk], rsn = rloc[tk];
    __bf16 outv[32];
#pragma unroll
    for (int j = 0; j < 32; ++j) {
      int c = cseg + j;
      outv[j] = (__bf16)((Xs[c][tk] - mun) * rsn * lnw[c] + lnb[c]);
    }
    __bf16* dst = &xln_t[((size_t)b * NN + n0 + tk) * CC + cseg];
#pragma unroll
    for (int q = 0; q < 4; ++q) *(bf16x8*)&dst[q * 8] = *(bf16x8*)&outv[q * 8];
  }
}

// ---------------------------------------------------------------------------
// Kernel 2: merged QKV GEMM (unchanged from R15).
// ---------------------------------------------------------------------------
__global__ __launch_bounds__(256, 3) void qkv_mfma_kernel(
    const __bf16* __restrict__ xln_t, const __bf16* __restrict__ wbf,
    const float* __restrict__ bias, __bf16* __restrict__ qt,
    __bf16* __restrict__ kt, __bf16* __restrict__ vbf) {
  __shared__ __align__(16) __bf16 As[2][64][64];
  __shared__ __align__(16) __bf16 Bs[2][128][64];
  int n0 = blockIdx.x * 128;
  bool swap = blockIdx.y < 16;
  int m0 = swap ? blockIdx.y * 64 : 1024 + ((int)blockIdx.y - 16) * 64;
  int b = blockIdx.z;
  int tid = threadIdx.x;
  int wid = tid >> 6, lane = tid & 63;
  int g = lane >> 4, c = lane & 15;
  int wr = wid >> 1, wc = wid & 1;
  const __bf16* xln = xln_t + (size_t)b * NN * CC;
  int l7 = lane & 7, l3 = lane >> 3;
  int xr = (l7 ^ l3) * 8;
  auto STAGE = [&](int buf, int k0) {
#pragma unroll
    for (int j = 0; j < 2; ++j) {
      int r = wid * 16 + 8 * j + l3;
      __builtin_amdgcn_global_load_lds(
          (guint*)(wbf + (size_t)(m0 + r) * CC + k0 + xr),
          (suint*)&As[buf][wid * 16 + 8 * j][0], 16, 0, 0);
    }
#pragma unroll
    for (int j = 0; j < 4; ++j) {
      int r = wid * 32 + 8 * j + l3;
      __builtin_amdgcn_global_load_lds(
          (guint*)(xln + (size_t)(n0 + r) * CC + k0 + xr),
          (suint*)&Bs[buf][wid * 32 + 8 * j][0], 16, 0, 0);
    }
  };
  STAGE(0, 0);
  f32x4 acc[2][4] = {};
  int cxor = c & 7;
  for (int ks = 0; ks < 8; ++ks) {
    int cur = ks & 1;
    if (ks < 7) {
      STAGE(cur ^ 1, (ks + 1) * 64);
      asm volatile("s_waitcnt vmcnt(6)" ::: "memory");
    } else {
      asm volatile("s_waitcnt vmcnt(0)" ::: "memory");
    }
    __builtin_amdgcn_sched_barrier(0);
    __builtin_amdgcn_s_barrier();
    __builtin_amdgcn_s_setprio(1);
#pragma unroll
    for (int hh = 0; hh < 2; ++hh) {
      int ch = ((hh * 4 + g) ^ cxor) * 8;
      bf16x8 af[2], bfr[4];
#pragma unroll
      for (int mi = 0; mi < 2; ++mi)
        af[mi] = *(const bf16x8*)&As[cur][wr * 32 + mi * 16 + c][ch];
#pragma unroll
      for (int nj = 0; nj < 4; ++nj)
        bfr[nj] = *(const bf16x8*)&Bs[cur][wc * 64 + nj * 16 + c][ch];
      if (swap) {
#pragma unroll
        for (int mi = 0; mi < 2; ++mi)
#pragma unroll
          for (int nj = 0; nj < 4; ++nj)
            acc[mi][nj] = __builtin_amdgcn_mfma_f32_16x16x32_bf16(
                bfr[nj], af[mi], acc[mi][nj], 0, 0, 0);
      } else {
#pragma unroll
        for (int mi = 0; mi < 2; ++mi)
#pragma unroll
          for (int nj = 0; nj < 4; ++nj)
            acc[mi][nj] = __builtin_amdgcn_mfma_f32_16x16x32_bf16(
                af[mi], bfr[nj], acc[mi][nj], 0, 0, 0);
      }
    }
    __builtin_amdgcn_s_setprio(0);
    __builtin_amdgcn_s_barrier();
  }
  if (swap) {
    int obase = m0 + wr * 32;
    int sec = obase >> 9;
    int osec = obase & 511;
    int head = osec >> 6;
    int dbase = osec & 63;
    __bf16* dst = (sec == 0 ? qt : kt) + (size_t)(b * NHEADS + head) * NN * HDIM;
    float scl = (sec == 0) ? QSCALE : 1.0f;
#pragma unroll
    for (int mi = 0; mi < 2; ++mi) {
      float bo = bias[obase + mi * 16 + c];
      int d = dbase + mi * 16 + c;
#pragma unroll
      for (int nj = 0; nj < 4; ++nj)
#pragma unroll
        for (int r = 0; r < 4; ++r) {
          int n = n0 + wc * 64 + nj * 16 + 4 * g + r;
          dst[(size_t)n * HDIM + d] = (__bf16)((acc[mi][nj][r] + bo) * scl);
        }
    }
  } else {
#pragma unroll
    for (int mi = 0; mi < 2; ++mi)
#pragma unroll
      for (int r = 0; r < 4; ++r) {
        int o = m0 + wr * 32 + mi * 16 + 4 * g + r;
        int ch = o - 1024;
        float bo = bias[o];
#pragma unroll
        for (int nj = 0; nj < 4; ++nj) {
          int n = n0 + wc * 64 + nj * 16 + c;
          vbf[((size_t)b * CC + ch) * NN + n] = (__bf16)(acc[mi][nj][r] + bo);
        }
      }
  }
}

// ---------------------------------------------------------------------------
// Kernel 3: flash attention (unchanged from R15).
// ---------------------------------------------------------------------------
__global__ __launch_bounds__(256, 3) void attn_mfma_kernel(
    const __bf16* __restrict__ qt, const __bf16* __restrict__ ktg,
    const __bf16* __restrict__ vbf, __bf16* __restrict__ opart,
    float* __restrict__ ml) {
  __shared__ __align__(16) __bf16 Kb[2][64][64];
  __shared__ __align__(16) __bf16 Vb[2][64][64];
  int tid = threadIdx.x;
  int wid = tid >> 6, lane = tid & 63;
  int g = lane >> 4, c = lane & 15;
  int n0 = blockIdx.x * 128;
  int h = blockIdx.y;
  int b = blockIdx.z >> 1, split = blockIdx.z & 1;
  int bh = b * NHEADS + h;
  const __bf16* qbase = qt + ((size_t)bh * NN + n0) * HDIM;
  const __bf16* kbase = ktg + ((size_t)bh * NN + split * KVQ) * HDIM;
  const __bf16* vbase = vbf + ((size_t)b * CC + h * HDIM) * NN + split * KVQ;

  int l7 = lane & 7, l3 = lane >> 3;
  int xr = (l7 ^ l3) * 8;
  auto STAGE = [&](int buf, int mt) {
#pragma unroll
    for (int j = 0; j < 2; ++j) {
      int r = wid * 16 + 8 * j + l3;
      int gr = (r & 0x20) | (((r >> 2) & 3) << 3) | (((r >> 4) & 1) << 2) | (r & 3);
      const __bf16* ksrc = kbase + (size_t)(mt + gr) * HDIM + xr;
      __builtin_amdgcn_global_load_lds((guint*)ksrc,
                                       (suint*)&Kb[buf][wid * 16 + 8 * j][0],
                                       16, 0, 0);
      const __bf16* vsrc = vbase + (size_t)r * NN + mt + xr;
      __builtin_amdgcn_global_load_lds((guint*)vsrc,
                                       (suint*)&Vb[buf][wid * 16 + 8 * j][0],
                                       16, 0, 0);
    }
  };

  STAGE(0, 0);
  bf16x8 aq[2][2];
#pragma unroll
  for (int qg = 0; qg < 2; ++qg) {
    const __bf16* qp = qbase + (size_t)(wid * 32 + qg * 16 + c) * HDIM;
    aq[qg][0] = *(const bf16x8*)(qp + g * 8);
    aq[qg][1] = *(const bf16x8*)(qp + 32 + g * 8);
  }
  f32x4 O[2][4] = {};
  f32x4 Ol[2] = {};
  float m_[2] = {-1e30f, -1e30f};
  int cxor = (c & 7);
  const bf16x8 vones = {(__bf16)1.f, (__bf16)1.f, (__bf16)1.f, (__bf16)1.f,
                        (__bf16)1.f, (__bf16)1.f, (__bf16)1.f, (__bf16)1.f};

  for (int t = 0; t < KVQ / 64; ++t) {
    int cur = t & 1;
    if (t + 1 < KVQ / 64) {
      STAGE(cur ^ 1, (t + 1) * 64);
      asm volatile("s_waitcnt vmcnt(4)" ::: "memory");
    } else {
      asm volatile("s_waitcnt vmcnt(0)" ::: "memory");
    }
    __builtin_amdgcn_sched_barrier(0);
    __builtin_amdgcn_s_barrier();
    f32x4 st[2][4];
    __builtin_amdgcn_s_setprio(1);
#pragma unroll
    for (int t4 = 0; t4 < 4; ++t4) {
      bf16x8 bk0 = *(const bf16x8*)&Kb[cur][t4 * 16 + c][(g ^ cxor) * 8];
      bf16x8 bk1 = *(const bf16x8*)&Kb[cur][t4 * 16 + c][((4 + g) ^ cxor) * 8];
#pragma unroll
      for (int qg = 0; qg < 2; ++qg) {
        f32x4 acc = {0.f, 0.f, 0.f, 0.f};
        acc = __builtin_amdgcn_mfma_f32_16x16x32_bf16(bk0, aq[qg][0], acc, 0, 0, 0);
        acc = __builtin_amdgcn_mfma_f32_16x16x32_bf16(bk1, aq[qg][1], acc, 0, 0, 0);
        st[qg][t4] = acc;
      }
    }
    __builtin_amdgcn_s_setprio(0);
    bf16x8 pa[2][2];
#pragma unroll
    for (int qg = 0; qg < 2; ++qg) {
      float g0 = MX3(st[qg][0][0], st[qg][0][1], st[qg][0][2]);
      float g1 = MX3(st[qg][0][3], st[qg][1][0], st[qg][1][1]);
      float g2 = MX3(st[qg][1][2], st[qg][1][3], st[qg][2][0]);
      float g3 = MX3(st[qg][2][1], st[qg][2][2], st[qg][2][3]);
      float g4 = MX3(st[qg][3][0], st[qg][3][1], st[qg][3][2]);
      float pm = fmaxf(MX3(g0, g1, g2), MX3(g3, g4, st[qg][3][3]));
      if (!__all(pm <= m_[qg] + 8.0f)) {
        float rm = fmaxf(pm, __shfl_xor(pm, 16));
        rm = fmaxf(rm, __shfl_xor(rm, 32));
        float mn = fmaxf(m_[qg], rm);
        float fs = exp2f(m_[qg] - mn);
        m_[qg] = mn;
#pragma unroll
        for (int dt = 0; dt < 4; ++dt)
#pragma unroll
          for (int r = 0; r < 4; ++r) O[qg][dt][r] *= fs;
#pragma unroll
        for (int r = 0; r < 4; ++r) Ol[qg][r] *= fs;
      }
#pragma unroll
      for (int t4 = 0; t4 < 4; ++t4) {
        float p0 = exp2f(st[qg][t4][0] - m_[qg]);
        float p1 = exp2f(st[qg][t4][1] - m_[qg]);
        float p2 = exp2f(st[qg][t4][2] - m_[qg]);
        float p3 = exp2f(st[qg][t4][3] - m_[qg]);
        bf16x8* pp = &pa[qg][t4 >> 1];
        int o4 = (t4 & 1) * 4;
        (*pp)[o4 + 0] = (__bf16)p0;
        (*pp)[o4 + 1] = (__bf16)p1;
        (*pp)[o4 + 2] = (__bf16)p2;
        (*pp)[o4 + 3] = (__bf16)p3;
      }
    }
    __builtin_amdgcn_s_setprio(1);
#pragma unroll
    for (int dt = 0; dt < 4; ++dt) {
      bf16x8 bv0 = *(const bf16x8*)&Vb[cur][dt * 16 + c][(g ^ cxor) * 8];
      bf16x8 bv1 = *(const bf16x8*)&Vb[cur][dt * 16 + c][((4 + g) ^ cxor) * 8];
#pragma unroll
      for (int qg = 0; qg < 2; ++qg) {
        O[qg][dt] = __builtin_amdgcn_mfma_f32_16x16x32_bf16(bv0, pa[qg][0],
                                                            O[qg][dt], 0, 0, 0);
        O[qg][dt] = __builtin_amdgcn_mfma_f32_16x16x32_bf16(bv1, pa[qg][1],
                                                            O[qg][dt], 0, 0, 0);
      }
    }
#pragma unroll
    for (int qg = 0; qg < 2; ++qg) {
      Ol[qg] = __builtin_amdgcn_mfma_f32_16x16x32_bf16(vones, pa[qg][0],
                                                       Ol[qg], 0, 0, 0);
      Ol[qg] = __builtin_amdgcn_mfma_f32_16x16x32_bf16(vones, pa[qg][1],
                                                       Ol[qg], 0, 0, 0);
    }
    __builtin_amdgcn_s_setprio(0);
    __builtin_amdgcn_s_barrier();
  }
#pragma unroll
  for (int qg = 0; qg < 2; ++qg) {
    size_t prow = ((size_t)(split * BB + b) * NHEADS + h) * NN +
                  (n0 + wid * 32 + qg * 16 + c);
#pragma unroll
    for (int dt = 0; dt < 4; ++dt) {
      bf16x4 pk = {(__bf16)O[qg][dt][0], (__bf16)O[qg][dt][1],
                   (__bf16)O[qg][dt][2], (__bf16)O[qg][dt][3]};
      *(bf16x4*)&opart[prow * HDIM + dt * 16 + 4 * g] = pk;
    }
    if (lane < 16) {
      float2 mlv = {m_[qg], Ol[qg][0]};
      *(float2*)&ml[prow * 2] = mlv;
    }
  }
}

// ---------------------------------------------------------------------------
// Kernel 4 (FUSED): proj GEMM consuming opart directly. Per K-step ks the
// k-slice is exactly head h=ks, so the B-tile is the normalized combine of
// the two splits' opart rows, computed in registers and ds_written to the
// swizzled LDS layout the MFMA reads expect (chunk^(row&7) — same involution
// as the read side). A stays global_load_lds. Epilogue: bias + LN residual.
// ---------------------------------------------------------------------------
__global__ __launch_bounds__(256, 4) void proj_fused_kernel(
    const __bf16* __restrict__ opart, const float* __restrict__ ml,
    const __bf16* __restrict__ wbf, const float* __restrict__ bias,
    const float* __restrict__ x, const float* __restrict__ mu,
    const float* __restrict__ rstd, const float* __restrict__ lnw,
    const float* __restrict__ lnb, float* __restrict__ out) {
  __shared__ __align__(16) __bf16 As[2][64][64];
  __shared__ __align__(16) __bf16 Bs[2][64][64];
  int n0 = blockIdx.x * 64;
  int m0 = blockIdx.y * 64;
  int b = blockIdx.z;
  int tid = threadIdx.x;
  int wid = tid >> 6, lane = tid & 63;
  int g = lane >> 4, c = lane & 15;
  int wr = wid >> 1, wc = wid & 1;
  int l7 = lane & 7, l3 = lane >> 3;
  int xr = (l7 ^ l3) * 8;
  auto STAGE_A = [&](int buf, int k0) {
#pragma unroll
    for (int j = 0; j < 2; ++j) {
      int r = wid * 16 + 8 * j + l3;
      __builtin_amdgcn_global_load_lds(
          (guint*)(wbf + (size_t)(m0 + r) * CC + k0 + xr),
          (suint*)&As[buf][wid * 16 + 8 * j][0], 16, 0, 0);
    }
  };
  // B staging: thread owns row rB = tid>>2, 16-col segment qB = tid&3
  int rB = tid >> 2, qB = tid & 3;
  bf16x8 b0[2], b1[2];
  float2 ml0, ml1;
  auto LOAD_B = [&](int h) {
    size_t p0 = ((size_t)(0 * BB + b) * NHEADS + h) * NN + n0 + rB;
    size_t p1 = ((size_t)(1 * BB + b) * NHEADS + h) * NN + n0 + rB;
    b0[0] = *(const bf16x8*)&opart[p0 * HDIM + qB * 16];
    b0[1] = *(const bf16x8*)&opart[p0 * HDIM + qB * 16 + 8];
    b1[0] = *(const bf16x8*)&opart[p1 * HDIM + qB * 16];
    b1[1] = *(const bf16x8*)&opart[p1 * HDIM + qB * 16 + 8];
    ml0 = *(const float2*)&ml[p0 * 2];
    ml1 = *(const float2*)&ml[p1 * 2];
  };
  auto WRITE_B = [&](int buf) {
    float mm = fmaxf(ml0.x, ml1.x);
    float w0 = exp2f(ml0.x - mm), w1 = exp2f(ml1.x - mm);
    float linv = 1.0f / (ml0.y * w0 + ml1.y * w1);
    w0 *= linv;
    w1 *= linv;
#pragma unroll
    for (int ch = 0; ch < 2; ++ch) {
      __bf16 ov[8];
#pragma unroll
      for (int j = 0; j < 8; ++j)
        ov[j] = (__bf16)((float)b0[ch][j] * w0 + (float)b1[ch][j] * w1);
      int chunk = (qB * 2 + ch) ^ (rB & 7);
      *(bf16x8*)&Bs[buf][rB][chunk * 8] = *(bf16x8*)&ov;
    }
  };

  // prologue: buffer 0
  LOAD_B(0);
  STAGE_A(0, 0);
  asm volatile("s_waitcnt vmcnt(0)" ::: "memory");
  __builtin_amdgcn_sched_barrier(0);
  WRITE_B(0);
  __syncthreads();

  f32x4 acc[2][2] = {};
  int cxor = c & 7;
  for (int ks = 0; ks < 8; ++ks) {
    int cur = ks & 1;
    if (ks < 7) {
      STAGE_A(cur ^ 1, (ks + 1) * 64);
      LOAD_B(ks + 1);
    }
    __builtin_amdgcn_s_setprio(1);
#pragma unroll
    for (int hh = 0; hh < 2; ++hh) {
      int ch = ((hh * 4 + g) ^ cxor) * 8;
      bf16x8 af[2], bfr[2];
#pragma unroll
      for (int mi = 0; mi < 2; ++mi)
        af[mi] = *(const bf16x8*)&As[cur][wr * 32 + mi * 16 + c][ch];
#pragma unroll
      for (int nj = 0; nj < 2; ++nj)
        bfr[nj] = *(const bf16x8*)&Bs[cur][wc * 32 + nj * 16 + c][ch];
#pragma unroll
      for (int mi = 0; mi < 2; ++mi)
#pragma unroll
        for (int nj = 0; nj < 2; ++nj)
          acc[mi][nj] = __builtin_amdgcn_mfma_f32_16x16x32_bf16(
              af[mi], bfr[nj], acc[mi][nj], 0, 0, 0);
    }
    __builtin_amdgcn_s_setprio(0);
    __builtin_amdgcn_s_barrier();  // all waves done reading buf[cur]
    if (ks < 7) {
      asm volatile("s_waitcnt vmcnt(0)" ::: "memory");  // A gload_lds landed
      __builtin_amdgcn_sched_barrier(0);
      WRITE_B(cur ^ 1);
      asm volatile("s_waitcnt lgkmcnt(0)" ::: "memory");  // writes visible
    }
    __builtin_amdgcn_s_barrier();  // buf[cur^1] fully ready
  }
#pragma unroll
  for (int mi = 0; mi < 2; ++mi)
#pragma unroll
    for (int r = 0; r < 4; ++r) {
      int o = m0 + wr * 32 + mi * 16 + 4 * g + r;
      float bo = bias[o], gw = lnw[o], gb = lnb[o];
#pragma unroll
      for (int nj = 0; nj < 2; ++nj) {
        int n = n0 + wc * 32 + nj * 16 + c;
        int tok = b * NN + n;
        float xv = x[((size_t)b * CC + o) * NN + n];
        float xlnv = (xv - mu[tok]) * rstd[tok] * gw + gb;
        out[((size_t)b * CC + o) * NN + n] = acc[mi][nj][r] + bo + xlnv;
      }
    }
}

// ---------------------------------------------------------------------------
extern "C" void kernel_launch(void* const* d_in, const int* in_sizes, int n_in,
                              void* d_out, int out_size, void* d_ws, size_t ws_size,
                              hipStream_t stream) {
  const float* x = (const float*)d_in[0];
  const float* lnw = (const float*)d_in[1];
  const float* lnb = (const float*)d_in[2];
  const float* wqkv = (const float*)d_in[3];
  const float* bqkv = (const float*)d_in[4];
  const float* wproj = (const float*)d_in[5];
  const float* bproj = (const float*)d_in[6];
  float* out = (float*)d_out;
  (void)in_sizes; (void)n_in; (void)out_size; (void)ws_size;

  char* wsb = (char*)d_ws;
  float* mu = (float*)wsb;                               // 16 KB
  float* rstd = mu + 4096;                               // 16 KB
  const size_t HSZ = (size_t)BB * NHEADS * NN * HDIM;    // 2M elems
  __bf16* qt = (__bf16*)(wsb + 32768);                   // 4 MB
  __bf16* kt = qt + HSZ;                                 // 4 MB
  __bf16* vbf = kt + HSZ;                                // 4 MB
  __bf16* xln_t = vbf + HSZ;                             // 4 MB
  __bf16* opart = xln_t + HSZ;                           // 2 x 4 MB = 8 MB
  float* ml = (float*)(opart + (size_t)NSPLIT * HSZ);    // 512 KB
  __bf16* wqkv_bf = (__bf16*)((char*)ml + 524288);       // 1.5 MB
  __bf16* wproj_bf = wqkv_bf + (size_t)3 * CC * CC;      // 0.5 MB
  // total ~26.6 MB

  hipLaunchKernelGGL(ln_cvt_kernel, dim3(1280), dim3(256), 0, stream,
                     x, lnw, lnb, wqkv, wproj, mu, rstd, xln_t, wqkv_bf,
                     wproj_bf);
  hipLaunchKernelGGL(qkv_mfma_kernel, dim3(16, 24, 2), dim3(256), 0, stream,
                     xln_t, wqkv_bf, bqkv, qt, kt, vbf);
  hipLaunchKernelGGL(attn_mfma_kernel, dim3(16, 8, BB * NSPLIT), dim3(256), 0,
                     stream, qt, kt, vbf, opart, ml);
  hipLaunchKernelGGL(proj_fused_kernel, dim3(32, 8, 2), dim3(256), 0, stream,
                     opart, ml, wproj_bf, bproj, x, mu, rstd, lnw, lnb, out);
}